// Round 22
// baseline (2734.755 us; speedup 1.0000x reference)
//
#include <hip/hip_runtime.h>
#include <hip/hip_bf16.h>
#include <math.h>

#define NBATCH 128
#define NATOM  80
#define SENC   80
#define SDEC   160
#define HGDIM  512
#define HIDDIM 256
#define NHEAD  8
#define ROWS_E (NBATCH*NATOM)   /* 10240 */
#define ROWS_D (NBATCH*SDEC)    /* 20480 */

typedef __hip_bfloat16 bf16;
typedef __attribute__((ext_vector_type(8))) short bf16x8;
typedef __attribute__((ext_vector_type(4))) float f32x4;

// ---------------- workspace layout (float units) ----------------
#define OFF_REAL 0ull
#define OFF_FLAG 10240ull
#define OFF_H    16384ull
#define OFF_QKVB (OFF_H   + 5242880ull)
#define OFF_DB   (OFF_QKVB+ 7864320ull)
#define OFF_LNB  (OFF_DB  + 6553600ull)
#define OFF_AOB  (OFF_LNB + 2621440ull)
#define OFF_MID  (OFF_AOB + 2621440ull)
#define OFF_MOM  (OFF_MID + 10485760ull)
#define OFF_KL   (OFF_MOM + 122880ull)
#define OFF_WT   (OFF_KL  + 64ull)
#define NEED_BYTES 184058112ull

// WT sub-offsets (bf16 element counts)
#define WT_EQKV 0ull
#define WT_EOUT 3145728ull
#define WT_EFF1 4194304ull
#define WT_EFF2 8388608ull
#define WT_PROJ 12582912ull
#define WT_DQKV 12713984ull
#define WT_DOW  14286848ull
#define WT_DFF1 14811136ull
#define WT_DFF2 16908288ull
#define WT_OA1  19005440ull

static __device__ __forceinline__ float bu2f(unsigned int u){
  union{unsigned int i; float f;} x; x.i = u<<16; return x.f;
}
static __device__ __forceinline__ unsigned short f2bu(float f){
  union{bf16 h; unsigned short u;} x; x.h = __float2bfloat16(f); return x.u;
}

// ---------------- misc kernels ----------------
__global__ void k_maskmode(const unsigned char* __restrict__ m, int* __restrict__ flag){
  __shared__ int sh[256];
  int loc = 0;
  for(int i=threadIdx.x; i<ROWS_E; i+=256)
    if((i&3)!=0 && m[i]) loc = 1;
  sh[threadIdx.x] = loc;
  __syncthreads();
  if(threadIdx.x==0){
    int a=0;
    for(int j=0;j<256;j++) a |= sh[j];
    *flag = a;
  }
}

__global__ void k_real(const unsigned char* __restrict__ m, const int* __restrict__ flag,
                       float* __restrict__ real){
  int i = blockIdx.x*256 + threadIdx.x;
  if(i >= ROWS_E) return;
  int v = (*flag) ? (int)m[i] : ((const int*)m)[i];
  real[i] = v ? 0.f : 1.f;
}

__global__ void k_wsfail(float* __restrict__ out, float code){
  if(threadIdx.x==0) out[0] = code;
}

// weight transpose+convert: src fp32 [L][K][N] -> dst bf16 [L][N][K]
__global__ __launch_bounds__(256) void k_wt(const float* __restrict__ src,
    bf16* __restrict__ dst, int K, int N){
  __shared__ float t[32][33];
  const float* s = src + (size_t)blockIdx.z*K*N;
  bf16* d = dst + (size_t)blockIdx.z*K*N;
  int n0 = blockIdx.x*32, k0 = blockIdx.y*32;
  int tx = threadIdx.x & 31, ty = threadIdx.x >> 5;
  #pragma unroll
  for(int kk=0;kk<32;kk+=8)
    t[kk+ty][tx] = s[(size_t)(k0+kk+ty)*N + n0+tx];
  __syncthreads();
  #pragma unroll
  for(int nn=0;nn<32;nn+=8)
    d[(size_t)(n0+nn+ty)*K + k0+tx] = __float2bfloat16(t[tx][nn+ty]);
}

__global__ void k_embed(const float* __restrict__ atom, const float* __restrict__ W,
                        float* __restrict__ h){
  int idx = blockIdx.x*256 + threadIdx.x;
  if(idx >= ROWS_E*HGDIM) return;
  int row = idx >> 9, c = idx & 511;
  float s = 0.f;
  #pragma unroll
  for(int a=0;a<16;a++) s += atom[row*16+a] * W[a*HGDIM+c];
  h[idx] = s;
}

// LN wave-per-row: fp32 in -> bf16 out. D in {256,512}. 4 rows/block.
__global__ __launch_bounds__(256) void k_ln4(const float* __restrict__ x,
    const float* __restrict__ g, const float* __restrict__ bta,
    bf16* __restrict__ y, int D){
  int row = blockIdx.x*4 + (threadIdx.x>>6);
  int lane = threadIdx.x & 63;
  const float* xr = x + (size_t)row*D;
  int nch = D >> 8;
  float4 v[2];
  float s=0.f, s2=0.f;
  for(int j=0;j<nch;j++){
    v[j] = *(const float4*)&xr[j*256 + lane*4];
    s  += v[j].x+v[j].y+v[j].z+v[j].w;
    s2 += v[j].x*v[j].x+v[j].y*v[j].y+v[j].z*v[j].z+v[j].w*v[j].w;
  }
  #pragma unroll
  for(int o=32;o>0;o>>=1){ s += __shfl_xor(s,o); s2 += __shfl_xor(s2,o); }
  float mean = s / D;
  float var  = fmaxf(s2 / D - mean*mean, 0.f);
  float inv  = rsqrtf(var + 1e-5f);
  for(int j=0;j<nch;j++){
    int c = j*256 + lane*4;
    ushort4 o4;
    o4.x = f2bu((v[j].x-mean)*inv*g[c]   + bta[c]);
    o4.y = f2bu((v[j].y-mean)*inv*g[c+1] + bta[c+1]);
    o4.z = f2bu((v[j].z-mean)*inv*g[c+2] + bta[c+2]);
    o4.w = f2bu((v[j].w-mean)*inv*g[c+3] + bta[c+3]);
    *(ushort4*)&y[(size_t)row*D + c] = o4;
  }
}

// LN wave-per-row: bf16 in -> bf16 out
__global__ __launch_bounds__(256) void k_ln4b(const bf16* __restrict__ x,
    const float* __restrict__ g, const float* __restrict__ bta,
    bf16* __restrict__ y, int D){
  int row = blockIdx.x*4 + (threadIdx.x>>6);
  int lane = threadIdx.x & 63;
  const unsigned short* xr = (const unsigned short*)(x + (size_t)row*D);
  int nch = D >> 8;
  float4 v[2];
  float s=0.f, s2=0.f;
  for(int j=0;j<nch;j++){
    ushort4 u = *(const ushort4*)&xr[j*256 + lane*4];
    v[j].x = bu2f(u.x); v[j].y = bu2f(u.y); v[j].z = bu2f(u.z); v[j].w = bu2f(u.w);
    s  += v[j].x+v[j].y+v[j].z+v[j].w;
    s2 += v[j].x*v[j].x+v[j].y*v[j].y+v[j].z*v[j].z+v[j].w*v[j].w;
  }
  #pragma unroll
  for(int o=32;o>0;o>>=1){ s += __shfl_xor(s,o); s2 += __shfl_xor(s2,o); }
  float mean = s / D;
  float var  = fmaxf(s2 / D - mean*mean, 0.f);
  float inv  = rsqrtf(var + 1e-5f);
  for(int j=0;j<nch;j++){
    int c = j*256 + lane*4;
    ushort4 o4;
    o4.x = f2bu((v[j].x-mean)*inv*g[c]   + bta[c]);
    o4.y = f2bu((v[j].y-mean)*inv*g[c+1] + bta[c+1]);
    o4.z = f2bu((v[j].z-mean)*inv*g[c+2] + bta[c+2]);
    o4.w = f2bu((v[j].w-mean)*inv*g[c+3] + bta[c+3]);
    *(ushort4*)&y[(size_t)row*D + c] = o4;
  }
}

// rbf attention bias for one encoder block
__global__ void k_db(const float* __restrict__ coord, const float* __restrict__ real,
                     const float* __restrict__ rbfw, float* __restrict__ db){
  int idx = blockIdx.x*256 + threadIdx.x;
  if(idx >= NBATCH*SENC*SENC) return;
  int b = idx/(SENC*SENC), r = idx%(SENC*SENC), q = r/SENC, k = r%SENC;
  float out[NHEAD];
  bool masked = (real[b*NATOM+k]==0.f) || (k==q);
  if(masked){
    #pragma unroll
    for(int h=0;h<NHEAD;h++) out[h] = -1e9f;
  } else {
    float dx = coord[(b*NATOM+q)*3+0] - coord[(b*NATOM+k)*3+0];
    float dy = coord[(b*NATOM+q)*3+1] - coord[(b*NATOM+k)*3+1];
    float dz = coord[(b*NATOM+q)*3+2] - coord[(b*NATOM+k)*3+2];
    float d  = sqrtf(dx*dx+dy*dy+dz*dz + 1e-12f);
    #pragma unroll
    for(int h=0;h<NHEAD;h++) out[h]=0.f;
    for(int rr=0;rr<16;rr++){
      float cen = (10.f/15.f)*rr;
      float e = __expf(-2.f*(d-cen)*(d-cen));
      #pragma unroll
      for(int h=0;h<NHEAD;h++) out[h] += e * rbfw[rr*NHEAD+h];
    }
  }
  #pragma unroll
  for(int h=0;h<NHEAD;h++)
    db[(((size_t)b*NHEAD+h)*SENC + q)*SENC + k] = out[h];
}

// ===== shared MFMA macro =====
#define MFMA_(acc, a, bfr) acc = __builtin_amdgcn_mfma_f32_16x16x32_bf16(a, bfr, acc, 0, 0, 0);

// ===== encoder attention v3: MFMA flash, block=(b,h), 4 waves =====
#define EQKT(kt, acc) { \
  bf16x8 bklo = *(const bf16x8*)&Ks[(kt)*16 + l15][g*8]; \
  bf16x8 bkhi = *(const bf16x8*)&Ks[(kt)*16 + l15][32 + g*8]; \
  MFMA_(acc, aqlo, bklo) MFMA_(acc, aqhi, bkhi) }
#define EBIAS(kt, sv) { \
  const float* dbr = dbb + (qt*16 + g*4)*80 + l15 + 16*(kt); \
  sv[0] = sv[0]*0.125f + dbr[0]; \
  sv[1] = sv[1]*0.125f + dbr[80]; \
  sv[2] = sv[2]*0.125f + dbr[160]; \
  sv[3] = sv[3]*0.125f + dbr[240]; }
#define EMAXJ(j) fmaxf(fmaxf(fmaxf(s0[j],s1[j]),fmaxf(s2[j],s3[j])),s4[j])
#define EEXP(sv) { sv[0]=__expf(sv[0]-m0); sv[1]=__expf(sv[1]-m1); sv[2]=__expf(sv[2]-m2); sv[3]=__expf(sv[3]-m3); }
#define ESUMJ(j) (s0[j]+s1[j]+s2[j]+s3[j]+s4[j])
#define ESTP(kt, sv) { \
  Pw[w][g*4+0][l15+16*(kt)] = f2bu(sv[0]); \
  Pw[w][g*4+1][l15+16*(kt)] = f2bu(sv[1]); \
  Pw[w][g*4+2][l15+16*(kt)] = f2bu(sv[2]); \
  Pw[w][g*4+3][l15+16*(kt)] = f2bu(sv[3]); }
#define EST(ov, ct) { \
  ob[0*HGDIM + (ct)*16 + l15] = __float2bfloat16(ov[0]*i0); \
  ob[1*HGDIM + (ct)*16 + l15] = __float2bfloat16(ov[1]*i1); \
  ob[2*HGDIM + (ct)*16 + l15] = __float2bfloat16(ov[2]*i2); \
  ob[3*HGDIM + (ct)*16 + l15] = __float2bfloat16(ov[3]*i3); }

__global__ __launch_bounds__(256) void k_attn_enc3(
    const bf16* __restrict__ qkvb, const float* __restrict__ db,
    bf16* __restrict__ o_out)
{
  __shared__ unsigned short Qs[80][72];
  __shared__ unsigned short Ks[80][72];
  __shared__ unsigned short Vt[64][104];
  __shared__ unsigned short Pw[4][16][104];
  int bh = blockIdx.x; int h = bh & 7, b = bh >> 3;
  const bf16* base = qkvb + (size_t)b*SENC*1536;
  const float* dbb = db + (size_t)bh*6400;
  int tid = threadIdx.x;
  int w = tid >> 6, lane = tid & 63;
  int l15 = lane & 15, g = lane >> 4;
  for(int c = tid; c < 640; c += 256){
    int r = c >> 3, p = c & 7;
    *(uint4*)&Qs[r][p*8] = *(const uint4*)(base + (size_t)r*1536 + h*64 + p*8);
    *(uint4*)&Ks[r][p*8] = *(const uint4*)(base + (size_t)r*1536 + 512 + h*64 + p*8);
  }
  for(int c = tid; c < 80*64; c += 256){
    int k = c >> 6, d = c & 63;
    Vt[d][k] = *(const unsigned short*)(base + (size_t)k*1536 + 1024 + h*64 + d);
  }
  for(int c = tid; c < 64*16; c += 256){
    int d = c >> 4, cc = c & 15;
    Vt[d][80+cc] = 0;
  }
  {
    int r = lane >> 2, c4 = (lane & 3)*4;
    ushort4 zz = {0,0,0,0};
    *(ushort4*)&Pw[w][r][80 + c4] = zz;
  }
  __syncthreads();
  for(int qt = w; qt < 5; qt += 4){
    bf16x8 aqlo = *(const bf16x8*)&Qs[qt*16 + l15][g*8];
    bf16x8 aqhi = *(const bf16x8*)&Qs[qt*16 + l15][32 + g*8];
    f32x4 z = {0.f,0.f,0.f,0.f};
    f32x4 s0=z,s1=z,s2=z,s3=z,s4=z;
    EQKT(0,s0) EQKT(1,s1) EQKT(2,s2) EQKT(3,s3) EQKT(4,s4)
    EBIAS(0,s0) EBIAS(1,s1) EBIAS(2,s2) EBIAS(3,s3) EBIAS(4,s4)
    float m0=EMAXJ(0), m1=EMAXJ(1), m2=EMAXJ(2), m3=EMAXJ(3);
    #pragma unroll
    for(int off=1; off<16; off<<=1){
      m0 = fmaxf(m0, __shfl_xor(m0, off));
      m1 = fmaxf(m1, __shfl_xor(m1, off));
      m2 = fmaxf(m2, __shfl_xor(m2, off));
      m3 = fmaxf(m3, __shfl_xor(m3, off));
    }
    EEXP(s0) EEXP(s1) EEXP(s2) EEXP(s3) EEXP(s4)
    float l0=ESUMJ(0), l1=ESUMJ(1), l2=ESUMJ(2), l3=ESUMJ(3);
    #pragma unroll
    for(int off=1; off<16; off<<=1){
      l0 += __shfl_xor(l0, off);
      l1 += __shfl_xor(l1, off);
      l2 += __shfl_xor(l2, off);
      l3 += __shfl_xor(l3, off);
    }
    ESTP(0,s0) ESTP(1,s1) ESTP(2,s2) ESTP(3,s3) ESTP(4,s4)
    f32x4 o0=z, o1=z, o2=z, o3=z;
    #pragma unroll
    for(int kc=0; kc<3; kc++){
      bf16x8 ap = *(const bf16x8*)&Pw[w][l15][kc*32 + g*8];
      bf16x8 v0 = *(const bf16x8*)&Vt[l15][kc*32 + g*8];
      bf16x8 v1 = *(const bf16x8*)&Vt[16 + l15][kc*32 + g*8];
      bf16x8 v2 = *(const bf16x8*)&Vt[32 + l15][kc*32 + g*8];
      bf16x8 v3 = *(const bf16x8*)&Vt[48 + l15][kc*32 + g*8];
      MFMA_(o0, ap, v0) MFMA_(o1, ap, v1) MFMA_(o2, ap, v2) MFMA_(o3, ap, v3)
    }
    float i0 = 1.f/l0, i1 = 1.f/l1, i2 = 1.f/l2, i3 = 1.f/l3;
    bf16* ob = o_out + ((size_t)(b*SENC + qt*16 + g*4))*HGDIM + h*64;
    EST(o0, 0) EST(o1, 1) EST(o2, 2) EST(o3, 3)
  }
}

// ===== decoder attention v5: MFMA flash attention, block=(b,h), 4 waves =====
#define QKT(kt, acc) { bf16x8 bk = *(const bf16x8*)&Ks[(kt)*16 + l15][g*8]; MFMA_(acc, aq, bk) }
#define SMSC(sv, mbv) { sv[0]=sv[0]*SCAL+(mbv); sv[1]=sv[1]*SCAL+(mbv); sv[2]=sv[2]*SCAL+(mbv); sv[3]=sv[3]*SCAL+(mbv); }
#define MAXJ(j) fmaxf(fmaxf(fmaxf(fmaxf(s0[j],s1[j]),fmaxf(s2[j],s3[j])),fmaxf(fmaxf(s4[j],s5[j]),fmaxf(s6[j],s7[j]))),fmaxf(s8[j],s9[j]))
#define EXPS(sv) { sv[0]=__expf(sv[0]-m0); sv[1]=__expf(sv[1]-m1); sv[2]=__expf(sv[2]-m2); sv[3]=__expf(sv[3]-m3); }
#define SUMJ(j) (s0[j]+s1[j]+s2[j]+s3[j]+s4[j]+s5[j]+s6[j]+s7[j]+s8[j]+s9[j])
#define STP(kt, sv) { \
  Pw[w][g*4+0][l15+16*(kt)] = f2bu(sv[0]); \
  Pw[w][g*4+1][l15+16*(kt)] = f2bu(sv[1]); \
  Pw[w][g*4+2][l15+16*(kt)] = f2bu(sv[2]); \
  Pw[w][g*4+3][l15+16*(kt)] = f2bu(sv[3]); }

__global__ __launch_bounds__(256) void k_attn_dec5(
    const bf16* __restrict__ qkvb, const float* __restrict__ real,
    bf16* __restrict__ o_out)
{
  __shared__ unsigned short Qs[160][40];
  __shared__ unsigned short Ks[160][40];
  __shared__ unsigned short Vt[32][168];
  __shared__ unsigned short Pw[4][16][168];
  __shared__ float mb[160];
  const float SCAL = 0.17677669529663689f;
  int bh = blockIdx.x; int h = bh & 7, b = bh >> 3;
  const bf16* base = qkvb + (size_t)b*SDEC*768;
  int tid = threadIdx.x;
  int w = tid >> 6, lane = tid & 63;
  int l15 = lane & 15, g = lane >> 4;
  for(int c = tid; c < 160*4; c += 256){
    int r = c >> 2, p = c & 3;
    *(uint4*)&Qs[r][p*8] = *(const uint4*)(base + (size_t)r*768 + h*32 + p*8);
    *(uint4*)&Ks[r][p*8] = *(const uint4*)(base + (size_t)r*768 + 256 + h*32 + p*8);
  }
  for(int c = tid; c < 160*32; c += 256){
    int k = c >> 5, d = c & 31;
    Vt[d][k] = *(const unsigned short*)(base + (size_t)k*768 + 512 + h*32 + d);
  }
  for(int k = tid; k < 160; k += 256){
    int kk = (k<80)?k:k-80;
    mb[k] = (real[b*NATOM+kk]==0.f) ? -1e9f : 0.f;
  }
  __syncthreads();
  float mb0=mb[l15],     mb1=mb[l15+16],  mb2=mb[l15+32],  mb3=mb[l15+48],  mb4=mb[l15+64];
  float mb5=mb[l15+80],  mb6=mb[l15+96],  mb7=mb[l15+112], mb8=mb[l15+128], mb9=mb[l15+144];
  for(int qt = w; qt < 10; qt += 4){
    bf16x8 aq = *(const bf16x8*)&Qs[qt*16 + l15][g*8];
    f32x4 z = {0.f,0.f,0.f,0.f};
    f32x4 s0=z,s1=z,s2=z,s3=z,s4=z,s5=z,s6=z,s7=z,s8=z,s9=z;
    QKT(0,s0) QKT(1,s1) QKT(2,s2) QKT(3,s3) QKT(4,s4)
    QKT(5,s5) QKT(6,s6) QKT(7,s7) QKT(8,s8) QKT(9,s9)
    SMSC(s0,mb0) SMSC(s1,mb1) SMSC(s2,mb2) SMSC(s3,mb3) SMSC(s4,mb4)
    SMSC(s5,mb5) SMSC(s6,mb6) SMSC(s7,mb7) SMSC(s8,mb8) SMSC(s9,mb9)
    float m0=MAXJ(0), m1=MAXJ(1), m2=MAXJ(2), m3=MAXJ(3);
    #pragma unroll
    for(int off=1; off<16; off<<=1){
      m0 = fmaxf(m0, __shfl_xor(m0, off));
      m1 = fmaxf(m1, __shfl_xor(m1, off));
      m2 = fmaxf(m2, __shfl_xor(m2, off));
      m3 = fmaxf(m3, __shfl_xor(m3, off));
    }
    EXPS(s0) EXPS(s1) EXPS(s2) EXPS(s3) EXPS(s4)
    EXPS(s5) EXPS(s6) EXPS(s7) EXPS(s8) EXPS(s9)
    float l0=SUMJ(0), l1=SUMJ(1), l2=SUMJ(2), l3=SUMJ(3);
    #pragma unroll
    for(int off=1; off<16; off<<=1){
      l0 += __shfl_xor(l0, off);
      l1 += __shfl_xor(l1, off);
      l2 += __shfl_xor(l2, off);
      l3 += __shfl_xor(l3, off);
    }
    STP(0,s0) STP(1,s1) STP(2,s2) STP(3,s3) STP(4,s4)
    STP(5,s5) STP(6,s6) STP(7,s7) STP(8,s8) STP(9,s9)
    f32x4 o0 = z, o1 = z;
    #pragma unroll
    for(int kt=0; kt<5; kt++){
      bf16x8 ap = *(const bf16x8*)&Pw[w][l15][kt*32 + g*8];
      bf16x8 v0 = *(const bf16x8*)&Vt[l15][kt*32 + g*8];
      bf16x8 v1 = *(const bf16x8*)&Vt[16 + l15][kt*32 + g*8];
      MFMA_(o0, ap, v0)
      MFMA_(o1, ap, v1)
    }
    float i0 = 1.f/l0, i1 = 1.f/l1, i2 = 1.f/l2, i3 = 1.f/l3;
    bf16* ob = o_out + ((size_t)(b*SDEC + qt*16 + g*4))*HIDDIM + h*32;
    ob[0*HIDDIM + l15]      = __float2bfloat16(o0[0]*i0);
    ob[1*HIDDIM + l15]      = __float2bfloat16(o0[1]*i1);
    ob[2*HIDDIM + l15]      = __float2bfloat16(o0[2]*i2);
    ob[3*HIDDIM + l15]      = __float2bfloat16(o0[3]*i3);
    ob[0*HIDDIM + 16 + l15] = __float2bfloat16(o1[0]*i0);
    ob[1*HIDDIM + 16 + l15] = __float2bfloat16(o1[1]*i1);
    ob[2*HIDDIM + 16 + l15] = __float2bfloat16(o1[2]*i2);
    ob[3*HIDDIM + 16 + l15] = __float2bfloat16(o1[3]*i3);
  }
}

// ===== MFMA bf16 GEMM v7: 128x128, BK=64, 3-bit swizzle, prefetch, XCD remap =====
#define MFM(accv, av, bv) accv = __builtin_amdgcn_mfma_f32_16x16x32_bf16(av, bv, accv, 0, 0, 0);
#define EPIM(accv, rr, cc) { \
  int col = col0 + (cc)*16 + l15; \
  float bi = bias ? bias[col] : 0.f; \
  _Pragma("unroll") \
  for(int j=0;j<4;j++){ \
    int row = row0 + w*32 + (rr)*16 + g*4 + j; \
    float v = accv[j] + bi; \
    if(resid) v += resid[(size_t)row*Nw + col]; \
    if(act==1) v = v/(1.f+__expf(-v)); \
    if(Cf) Cf[(size_t)row*Nw + col] = v; \
    else   Cb[(size_t)row*Nw + col] = __float2bfloat16(v); } }

#define SUBSTEP(s) { \
  int ch = ((s)*4 + g) ^ sw7; \
  bf16x8 a0 = *(const bf16x8*)&As4[w*32 + l15][ch]; \
  bf16x8 a1 = *(const bf16x8*)&As4[w*32 + 16 + l15][ch]; \
  bf16x8 b0 = *(const bf16x8*)&Bs4[l15][ch]; \
  bf16x8 b1 = *(const bf16x8*)&Bs4[16 + l15][ch]; \
  bf16x8 b2 = *(const bf16x8*)&Bs4[32 + l15][ch]; \
  bf16x8 b3 = *(const bf16x8*)&Bs4[48 + l15][ch]; \
  bf16x8 b4 = *(const bf16x8*)&Bs4[64 + l15][ch]; \
  bf16x8 b5 = *(const bf16x8*)&Bs4[80 + l15][ch]; \
  bf16x8 b6 = *(const bf16x8*)&Bs4[96 + l15][ch]; \
  bf16x8 b7 = *(const bf16x8*)&Bs4[112 + l15][ch]; \
  MFM(c00, a0, b0) MFM(c01, a0, b1) MFM(c02, a0, b2) MFM(c03, a0, b3) \
  MFM(c04, a0, b4) MFM(c05, a0, b5) MFM(c06, a0, b6) MFM(c07, a0, b7) \
  MFM(c10, a1, b0) MFM(c11, a1, b1) MFM(c12, a1, b2) MFM(c13, a1, b3) \
  MFM(c14, a1, b4) MFM(c15, a1, b5) MFM(c16, a1, b6) MFM(c17, a1, b7) }

__global__ __launch_bounds__(256) void k_gemm_mfma7(
    const bf16* __restrict__ A, const bf16* __restrict__ WT,
    const float* __restrict__ bias, const float* __restrict__ resid,
    float* __restrict__ Cf, bf16* __restrict__ Cb,
    int M, int K, int Nw, int act)
{
  __shared__ uint4 As4[128][8];
  __shared__ uint4 Bs4[128][8];
  int tid = threadIdx.x;
  int w = tid >> 6, lane = tid & 63;
  int l15 = lane & 15, g = lane >> 4;
  int lin = blockIdx.x + gridDim.x*blockIdx.y;
  int bcol = lin / gridDim.y;
  int brw  = lin - bcol*gridDim.y;
  int row0 = brw*128, col0 = bcol*128;
  int arow = tid >> 1, ahalf = tid & 1;
  int swr = arow & 7;
  int sw7 = l15 & 7;
  int bb = ahalf*4;
  const bf16* aP = A  + (size_t)(row0+arow)*K + ahalf*32;
  const bf16* bP = WT + (size_t)(col0+arow)*K + ahalf*32;
  f32x4 z = {0.f,0.f,0.f,0.f};
  f32x4 c00=z,c01=z,c02=z,c03=z,c04=z,c05=z,c06=z,c07=z;
  f32x4 c10=z,c11=z,c12=z,c13=z,c14=z,c15=z,c16=z,c17=z;
  uint4 av0,av1,av2,av3,bv0,bv1,bv2,bv3;
  {
    const uint4* asrc = (const uint4*)aP;
    const uint4* bsrc = (const uint4*)bP;
    av0=asrc[0]; av1=asrc[1]; av2=asrc[2]; av3=asrc[3];
    bv0=bsrc[0]; bv1=bsrc[1]; bv2=bsrc[2]; bv3=bsrc[3];
  }
  for(int k0=0;k0<K;k0+=64){
    As4[arow][(bb+0)^swr] = av0;
    As4[arow][(bb+1)^swr] = av1;
    As4[arow][(bb+2)^swr] = av2;
    As4[arow][(bb+3)^swr] = av3;
    Bs4[arow][(bb+0)^swr] = bv0;
    Bs4[arow][(bb+1)^swr] = bv1;
    Bs4[arow][(bb+2)^swr] = bv2;
    Bs4[arow][(bb+3)^swr] = bv3;
    __syncthreads();
    int kn = k0 + 64;
    if(kn < K){
      const uint4* asrc = (const uint4*)(aP + kn);
      const uint4* bsrc = (const uint4*)(bP + kn);
      av0=asrc[0]; av1=asrc[1]; av2=asrc[2]; av3=asrc[3];
      bv0=bsrc[0]; bv1=bsrc[1]; bv2=bsrc[2]; bv3=bsrc[3];
    }
    SUBSTEP(0)
    SUBSTEP(1)
    __syncthreads();
  }
  EPIM(c00, 0, 0) EPIM(c01, 0, 1) EPIM(c02, 0, 2) EPIM(c03, 0, 3)
  EPIM(c04, 0, 4) EPIM(c05, 0, 5) EPIM(c06, 0, 6) EPIM(c07, 0, 7)
  EPIM(c10, 1, 0) EPIM(c11, 1, 1) EPIM(c12, 1, 2) EPIM(c13, 1, 3)
  EPIM(c14, 1, 4) EPIM(c15, 1, 5) EPIM(c16, 1, 6) EPIM(c17, 1, 7)
}

// ===== MFMA bf16 GEMM v10: 64x128, BK=64, depth-2 register prefetch =====
#define EPIM8(accv, rr, cc) { \
  int col = col0 + w*32 + (cc)*16 + l15; \
  float bi = bias ? bias[col] : 0.f; \
  _Pragma("unroll") \
  for(int j=0;j<4;j++){ \
    int row = row0 + (rr)*16 + g*4 + j; \
    float v = accv[j] + bi; \
    if(resid) v += resid[(size_t)row*Nw + col]; \
    if(act==1) v = v/(1.f+__expf(-v)); \
    if(Cf) Cf[(size_t)row*Nw + col] = v; \
    else   Cb[(size_t)row*Nw + col] = __float2bfloat16(v); } }

#define SUBSTEP8(s) { \
  int ch = ((s)*4 + g) ^ sw7; \
  bf16x8 a0 = *(const bf16x8*)&As4[l15][ch]; \
  bf16x8 a1 = *(const bf16x8*)&As4[16 + l15][ch]; \
  bf16x8 a2 = *(const bf16x8*)&As4[32 + l15][ch]; \
  bf16x8 a3 = *(const bf16x8*)&As4[48 + l15][ch]; \
  bf16x8 b0 = *(const bf16x8*)&Bs4[w*32 + l15][ch]; \
  bf16x8 b1 = *(const bf16x8*)&Bs4[w*32 + 16 + l15][ch]; \
  MFM(c00, a0, b0) MFM(c01, a0, b1) \
  MFM(c10, a1, b0) MFM(c11, a1, b1) \
  MFM(c20, a2, b0) MFM(c21, a2, b1) \
  MFM(c30, a3, b0) MFM(c31, a3, b1) }

#define LOADSET(aw0, aw1, bw0, bw1, bw2, bw3, koff) { \
  const uint4* asrc = (const uint4*)(aP + (koff)); \
  const uint4* bsrc = (const uint4*)(bP + (koff)); \
  aw0=asrc[0]; aw1=asrc[1]; \
  bw0=bsrc[0]; bw1=bsrc[1]; bw2=bsrc[2]; bw3=bsrc[3]; }

#define STORESET(aw0, aw1, bw0, bw1, bw2, bw3) { \
  As4[arow4][(2*aq+0)^swA] = aw0; \
  As4[arow4][(2*aq+1)^swA] = aw1; \
  Bs4[brow][(bbp+0)^swB] = bw0; \
  Bs4[brow][(bbp+1)^swB] = bw1; \
  Bs4[brow][(bbp+2)^swB] = bw2; \
  Bs4[brow][(bbp+3)^swB] = bw3; }

__global__ __launch_bounds__(256) void k_gemm_mfma10(
    const bf16* __restrict__ A, const bf16* __restrict__ WT,
    const float* __restrict__ bias, const float* __restrict__ resid,
    float* __restrict__ Cf, bf16* __restrict__ Cb,
    int M, int K, int Nw, int act)
{
  __shared__ uint4 As4[64][8];
  __shared__ uint4 Bs4[128][8];
  int tid = threadIdx.x;
  int w = tid >> 6, lane = tid & 63;
  int l15 = lane & 15, g = lane >> 4;
  int lin = blockIdx.x + gridDim.x*blockIdx.y;
  int bcol = lin / gridDim.y;
  int brw  = lin - bcol*gridDim.y;
  int row0 = brw*64, col0 = bcol*128;
  int arow4 = tid >> 2, aq = tid & 3;
  int swA = arow4 & 7;
  int brow = tid >> 1, bhalf = tid & 1;
  int swB = brow & 7;
  int sw7 = l15 & 7;
  int bbp = bhalf*4;
  const bf16* aP = A  + (size_t)(row0+arow4)*K + aq*16;
  const bf16* bP = WT + (size_t)(col0+brow)*K + bhalf*32;
  f32x4 z = {0.f,0.f,0.f,0.f};
  f32x4 c00=z,c01=z,c10=z,c11=z,c20=z,c21=z,c30=z,c31=z;
  uint4 aA0,aA1,bA0,bA1,bA2,bA3;
  uint4 aB0,aB1,bB0,bB1,bB2,bB3;
  LOADSET(aA0,aA1,bA0,bA1,bA2,bA3, 0)
  LOADSET(aB0,aB1,bB0,bB1,bB2,bB3, 64)
  for(int k0=0;k0<K;k0+=128){
    // tile k0 (set A)
    STORESET(aA0,aA1,bA0,bA1,bA2,bA3)
    __syncthreads();
    if(k0+128 < K){ LOADSET(aA0,aA1,bA0,bA1,bA2,bA3, k0+128) }
    SUBSTEP8(0)
    SUBSTEP8(1)
    __syncthreads();
    // tile k0+64 (set B)
    STORESET(aB0,aB1,bB0,bB1,bB2,bB3)
    __syncthreads();
    if(k0+192 < K){ LOADSET(aB0,aB1,bB0,bB1,bB2,bB3, k0+192) }
    SUBSTEP8(0)
    SUBSTEP8(1)
    __syncthreads();
  }
  EPIM8(c00, 0, 0) EPIM8(c01, 0, 1)
  EPIM8(c10, 1, 0) EPIM8(c11, 1, 1)
  EPIM8(c20, 2, 0) EPIM8(c21, 2, 1)
  EPIM8(c30, 3, 0) EPIM8(c31, 3, 1)
}

// ===== tiny-N GEMM: 16 rows/block, A tile + W staged in LDS, K=256, Nw<=16 =====
__global__ __launch_bounds__(256) void k_gemm_tiny(
    const bf16* __restrict__ A, const float* __restrict__ W,
    const float* __restrict__ bias, float* __restrict__ C,
    int Nw, int act)
{
  __shared__ unsigned short As[16][264];
  __shared__ float Ws[4096];
  int tid = threadIdx.x;
  int row0 = blockIdx.x*16;
  int ar = tid >> 4, ac = (tid & 15) * 16;
  const uint4* asrc = (const uint4*)(A + (size_t)(row0+ar)*256 + ac);
  *(uint4*)&As[ar][ac]   = asrc[0];
  *(uint4*)&As[ar][ac+8] = asrc[1];
  int wtot = 256*Nw;
  for(int i=tid; i<wtot; i+=256) Ws[i] = W[i];
  __syncthreads();
  int row = tid >> 4, col = tid & 15;
  if(col < Nw){
    float acc = bias ? bias[col] : 0.f;
    #pragma unroll 8
    for(int k=0;k<256;k++)
      acc += bu2f(As[row][k]) * Ws[k*Nw+col];
    if(act==1) acc = acc/(1.f+__expf(-acc));
    C[(size_t)(row0+row)*Nw + col] = acc;
  }
}

__global__ __launch_bounds__(256) void k_kl(const float* __restrict__ mom,
    const float* __restrict__ real, float* __restrict__ part){
  int i = blockIdx.x*256 + threadIdx.x;
  float s = 0.f;
  if(i < ROWS_E){
    const float* m = mom + (size_t)i*12;
    float acc = 0.f;
    #pragma unroll
    for(int d=0;d<6;d++){ float mu=m[d], lv=m[6+d]; acc += 1.f + lv - mu*mu - expf(lv); }
    s = acc * real[i];
  }
  #pragma unroll
  for(int o=32;o>0;o>>=1) s += __shfl_xor(s,o);
  __shared__ float r[4];
  if((threadIdx.x&63)==0) r[threadIdx.x>>6]=s;
  __syncthreads();
  if(threadIdx.x==0) part[blockIdx.x] = r[0]+r[1]+r[2]+r[3];
}

__global__ void k_klfin(const float* __restrict__ part, float* __restrict__ o){
  float s=0.f;
  for(int i=0;i<40;i++) s += part[i];
  *o = -0.5f * (s/(float)ROWS_E) * 1e-6f;
}

// h*real -> bf16
__global__ void k_cvtrs(const float* __restrict__ h, const float* __restrict__ real,
                        bf16* __restrict__ o){
  int idx = blockIdx.x*256 + threadIdx.x;
  if(idx >= ROWS_E*HGDIM) return;
  int row = idx >> 9;
  o[idx] = __float2bfloat16(h[idx]*real[row]);
}

__global__ __launch_bounds__(256) void k_build_x(
  const float* __restrict__ coord_t, const float* __restrict__ atomics_t, const float* __restrict__ tin,
  const float* __restrict__ qout_w, const float* __restrict__ qout_b, const float* __restrict__ cond,
  const float* __restrict__ lin_w, const float* __restrict__ atom_emb,
  const float* __restrict__ mom, const float* __restrict__ real, float* __restrict__ x)
{
  int idx = blockIdx.x*256 + threadIdx.x;
  if(idx >= NBATCH*SDEC*HIDDIM) return;
  int c = idx & 255; int rowg = idx >> 8; int s = rowg % SDEC; int b = rowg / SDEC;
  int n = (s<NATOM)? s : s-NATOM;
  int j = c >> 1;
  float div = __expf(-(float)(2*j) * (9.210340371976184f/256.f));
  float ang = (float)n * div;
  float pe = (c & 1) ? __cosf(ang) : __sinf(ang);
  float rl = real[b*NATOM + n];
  float v;
  if(s < NATOM){
    int rown = b*NATOM + n;
    float cl = 0.f;
    #pragma unroll
    for(int a=0;a<3;a++) cl += coord_t[rown*3+a] * lin_w[a*HIDDIM+c];
    int bi=0; float bv = atomics_t[rown*16];
    for(int a=1;a<16;a++){ float vv=atomics_t[rown*16+a]; if(vv>bv){bv=vv; bi=a;} }
    float ae = atom_emb[bi*HIDDIM+c];
    float tb = tin[b];
    float tf;
    if(c < 128){
      float fr = __expf(-(float)c * (5.298317366548036f/128.f));
      tf = __sinf(tb*200.f*fr);
    } else {
      float fr = __expf(-(float)(c-128) * (5.298317366548036f/128.f));
      tf = __cosf(tb*200.f*fr);
    }
    v = (cl + ae + pe + tf)*rl + cond[c];
  } else {
    int rown = b*NATOM + n;
    const float* mp = mom + (size_t)rown*12;
    float s2 = qout_b[c];
    #pragma unroll
    for(int d=0;d<6;d++) s2 += mp[d]*qout_w[d*HIDDIM+c];
    v = (s2 + pe)*rl + cond[HIDDIM+c];
  }
  x[idx] = v;
}

// h_out -> bf16 only
__global__ void k_hout(const float* __restrict__ x, const float* __restrict__ real,
                       bf16* __restrict__ h_out_b){
  int idx = blockIdx.x*256 + threadIdx.x;
  if(idx >= ROWS_E*HIDDIM) return;
  int c = idx & 255, row = idx >> 8;
  int n = row % NATOM, b = row / NATOM;
  float v = x[((size_t)(b*SDEC+n))*HIDDIM + c] * real[row];
  h_out_b[idx] = __float2bfloat16(v);
}

// ---------------- launch ----------------
extern "C" void kernel_launch(void* const* d_in, const int* in_sizes, int n_in,
                              void* d_out, int out_size, void* d_ws, size_t ws_size,
                              hipStream_t stream){
  (void)in_sizes; (void)n_in; (void)out_size;
  const float* coord_ori   = (const float*)d_in[0];
  const float* atomics_ori = (const float*)d_in[1];
  const unsigned char* pmask = (const unsigned char*)d_in[2];
  const float* coord_t     = (const float*)d_in[3];
  const float* atomics_t   = (const float*)d_in[4];
  const float* t_in        = (const float*)d_in[5];
  const float* enc_embed_w = (const float*)d_in[6];
  const float* rbf_w       = (const float*)d_in[7];
  const float* e_qkv_w=(const float*)d_in[8];  const float* e_qkv_b=(const float*)d_in[9];
  const float* e_out_w=(const float*)d_in[10]; const float* e_out_b=(const float*)d_in[11];
  const float* e_ff1_w=(const float*)d_in[12]; const float* e_ff1_b=(const float*)d_in[13];
  const float* e_ff2_w=(const float*)d_in[14]; const float* e_ff2_b=(const float*)d_in[15];
  const float* e_ln1_g=(const float*)d_in[16]; const float* e_ln1_b=(const float*)d_in[17];
  const float* e_ln2_g=(const float*)d_in[18]; const float* e_ln2_b=(const float*)d_in[19];
  const float* enc_proj_w=(const float*)d_in[20];
  const float* quant_w=(const float*)d_in[21]; const float* quant_b=(const float*)d_in[22];
  const float* qout_w=(const float*)d_in[23];  const float* qout_b=(const float*)d_in[24];
  const float* cond_embed=(const float*)d_in[25];
  const float* lin_embed_w=(const float*)d_in[26];
  const float* atom_embed=(const float*)d_in[27];
  const float* d_qkv_w=(const float*)d_in[28]; const float* d_qkv_b=(const float*)d_in[29];
  const float* d_ow   =(const float*)d_in[30]; const float* d_ob   =(const float*)d_in[31];
  const float* d_ff1_w=(const float*)d_in[32]; const float* d_ff1_b=(const float*)d_in[33];
  const float* d_ff2_w=(const float*)d_in[34]; const float* d_ff2_b=(const float*)d_in[35];
  const float* d_ln1_g=(const float*)d_in[36]; const float* d_ln1_b=(const float*)d_in[37];
  const float* d_ln2_g=(const float*)d_in[38]; const float* d_ln2_b=(const float*)d_in[39];
  const float* oc_ln_g=(const float*)d_in[40]; const float* oc_ln_b=(const float*)d_in[41];
  const float* oc_w   =(const float*)d_in[42];
  const float* oa1_w  =(const float*)d_in[43]; const float* oa1_b=(const float*)d_in[44];
  const float* oa2_w  =(const float*)d_in[45]; const float* oa2_b=(const float*)d_in[46];

  float* ws   = (float*)d_ws;
  float* real = ws + OFF_REAL;
  int*   flag = (int*)(ws + OFF_FLAG);
  float* h    = ws + OFF_H;
  bf16*  qkvb = (bf16*)(ws + OFF_QKVB);
  float* db   = ws + OFF_DB;
  bf16*  lnb  = (bf16*)(ws + OFF_LNB);
  bf16*  aob  = (bf16*)(ws + OFF_AOB);
  bf16*  mid  = (bf16*)(ws + OFF_MID);
  float* mom  = ws + OFF_MOM;
  float* klp  = ws + OFF_KL;
  bf16*  wt   = (bf16*)(ws + OFF_WT);
  float* out  = (float*)d_out;

  if(ws_size < NEED_BYTES){
    k_wsfail<<<1,64,0,stream>>>(out, 1.0e6f + (float)(ws_size>>20));
    return;
  }

  // one-time weight transposes (fp32 [K][N] -> bf16 [N][K])
  k_wt<<<dim3(48,16,4),256,0,stream>>>(e_qkv_w,  wt+WT_EQKV, 512, 1536);
  k_wt<<<dim3(16,16,4),256,0,stream>>>(e_out_w,  wt+WT_EOUT, 512, 512);
  k_wt<<<dim3(64,16,4),256,0,stream>>>(e_ff1_w,  wt+WT_EFF1, 512, 2048);
  k_wt<<<dim3(16,64,4),256,0,stream>>>(e_ff2_w,  wt+WT_EFF2, 2048, 512);
  k_wt<<<dim3(8,16,1), 256,0,stream>>>(enc_proj_w, wt+WT_PROJ, 512, 256);
  k_wt<<<dim3(24,8,8), 256,0,stream>>>(d_qkv_w,  wt+WT_DQKV, 256, 768);
  k_wt<<<dim3(8,8,8),  256,0,stream>>>(d_ow,     wt+WT_DOW,  256, 256);
  k_wt<<<dim3(32,8,8), 256,0,stream>>>(d_ff1_w,  wt+WT_DFF1, 256, 1024);
  k_wt<<<dim3(8,32,8), 256,0,stream>>>(d_ff2_w,  wt+WT_DFF2, 1024, 256);
  k_wt<<<dim3(8,8,1),  256,0,stream>>>(oa1_w,    wt+WT_OA1,  256, 256);

  k_maskmode<<<1,256,0,stream>>>(pmask, flag);
  k_real <<<40,   256, 0, stream>>>(pmask, flag, real);
  k_embed<<<20480,256, 0, stream>>>(atomics_ori, enc_embed_w, h);

  // ===== encoder =====
  for(int i=0;i<4;i++){
    k_ln4<<<ROWS_E/4,256,0,stream>>>(h, e_ln1_g+i*HGDIM, e_ln1_b+i*HGDIM, lnb, HGDIM);
    k_gemm_mfma7<<<dim3(12,80),256,0,stream>>>(lnb, wt+WT_EQKV+(size_t)i*512*1536,
        e_qkv_b+i*3*HGDIM, nullptr, nullptr, qkvb, ROWS_E, HGDIM, 3*HGDIM, 0);
    k_db<<<3200,256,0,stream>>>(coord_ori, real, rbf_w + i*16*NHEAD, db);
    k_attn_enc3<<<NBATCH*NHEAD,256,0,stream>>>(qkvb, db, aob);
    k_gemm_mfma10<<<dim3(4,160),256,0,stream>>>(aob, wt+WT_EOUT+(size_t)i*512*512,
        e_out_b+i*HGDIM, h, h, nullptr, ROWS_E, HGDIM, HGDIM, 0);
    k_ln4<<<ROWS_E/4,256,0,stream>>>(h, e_ln2_g+i*HGDIM, e_ln2_b+i*HGDIM, lnb, HGDIM);
    k_gemm_mfma7<<<dim3(16,80),256,0,stream>>>(lnb, wt+WT_EFF1+(size_t)i*512*2048,
        e_ff1_b+i*4*HGDIM, nullptr, nullptr, mid, ROWS_E, HGDIM, 4*HGDIM, 1);
    k_gemm_mfma10<<<dim3(4,160),256,0,stream>>>(mid, wt+WT_EFF2+(size_t)i*2048*512,
        e_ff2_b+i*HGDIM, h, h, nullptr, ROWS_E, 4*HGDIM, HGDIM, 0);
  }

  k_cvtrs<<<20480,256,0,stream>>>(h, real, lnb);
  k_gemm_mfma10<<<dim3(2,160),256,0,stream>>>(lnb, wt+WT_PROJ,
      nullptr, nullptr, nullptr, aob, ROWS_E, HGDIM, HIDDIM, 0);
  k_gemm_tiny<<<640,256,0,stream>>>(aob, quant_w, quant_b, mom, 12, 0);
  k_kl   <<<40,256,0,stream>>>(mom, real, klp);
  k_klfin<<<1,1,0,stream>>>(klp, out + 194560);

  k_build_x<<<20480,256,0,stream>>>(coord_t, atomics_t, t_in, qout_w, qout_b,
      cond_embed, lin_embed_w, atom_embed, mom, real, h);

  // ===== decoder =====
  for(int i=0;i<8;i++){
    k_ln4<<<ROWS_D/4,256,0,stream>>>(h, d_ln1_g+i*HIDDIM, d_ln1_b+i*HIDDIM, lnb, HIDDIM);
    k_gemm_mfma10<<<dim3(6,320),256,0,stream>>>(lnb, wt+WT_DQKV+(size_t)i*256*768,
        d_qkv_b+i*3*HIDDIM, nullptr, nullptr, qkvb, ROWS_D, HIDDIM, 3*HIDDIM, 0);
    k_attn_dec5<<<NBATCH*NHEAD,256,0,stream>>>(qkvb, real, aob);
    k_gemm_mfma10<<<dim3(2,320),256,0,stream>>>(aob, wt+WT_DOW+(size_t)i*256*256,
        d_ob+i*HIDDIM, h, h, nullptr, ROWS_D, HIDDIM, HIDDIM, 0);
    k_ln4<<<ROWS_D/4,256,0,stream>>>(h, d_ln2_g+i*HIDDIM, d_ln2_b+i*HIDDIM, lnb, HIDDIM);
    k_gemm_mfma7<<<dim3(8,160),256,0,stream>>>(lnb, wt+WT_DFF1+(size_t)i*256*1024,
        d_ff1_b+i*4*HIDDIM, nullptr, nullptr, mid, ROWS_D, HIDDIM, 4*HIDDIM, 1);
    k_gemm_mfma10<<<dim3(2,320),256,0,stream>>>(mid, wt+WT_DFF2+(size_t)i*1024*256,
        d_ff2_b+i*HIDDIM, h, h, nullptr, ROWS_D, 4*HIDDIM, HIDDIM, 0);
  }

  // ===== heads =====
  k_hout<<<10240,256,0,stream>>>(h, real, aob);
  k_ln4b<<<ROWS_E/4,256,0,stream>>>(aob, oc_ln_g, oc_ln_b, lnb, HIDDIM);
  k_gemm_tiny<<<640,256,0,stream>>>(lnb, oc_w, nullptr, out, 3, 0);
  k_gemm_mfma10<<<dim3(2,160),256,0,stream>>>(aob, wt+WT_OA1, oa1_b, nullptr,
      nullptr, mid, ROWS_E, HIDDIM, HIDDIM, 1);
  k_gemm_tiny<<<640,256,0,stream>>>(mid, oa2_w, oa2_b, out + 30720, 16, 0);
}

// Round 23
// 2597.376 us; speedup vs baseline: 1.0529x; 1.0529x over previous
//
#include <hip/hip_runtime.h>
#include <hip/hip_bf16.h>
#include <math.h>

#define NBATCH 128
#define NATOM  80
#define SENC   80
#define SDEC   160
#define HGDIM  512
#define HIDDIM 256
#define NHEAD  8
#define ROWS_E (NBATCH*NATOM)   /* 10240 */
#define ROWS_D (NBATCH*SDEC)    /* 20480 */

typedef __hip_bfloat16 bf16;
typedef __attribute__((ext_vector_type(8))) short bf16x8;
typedef __attribute__((ext_vector_type(4))) float f32x4;

// ---------------- workspace layout (float units) ----------------
#define OFF_REAL 0ull
#define OFF_FLAG 10240ull
#define OFF_H    16384ull
#define OFF_QKVB (OFF_H   + 5242880ull)
#define OFF_DB   (OFF_QKVB+ 7864320ull)
#define OFF_LNB  (OFF_DB  + 6553600ull)
#define OFF_AOB  (OFF_LNB + 2621440ull)
#define OFF_MID  (OFF_AOB + 2621440ull)
#define OFF_MOM  (OFF_MID + 10485760ull)
#define OFF_KL   (OFF_MOM + 122880ull)
#define OFF_WT   (OFF_KL  + 64ull)
#define NEED_BYTES 184058112ull

// WT sub-offsets (bf16 element counts)
#define WT_EQKV 0ull
#define WT_EOUT 3145728ull
#define WT_EFF1 4194304ull
#define WT_EFF2 8388608ull
#define WT_PROJ 12582912ull
#define WT_DQKV 12713984ull
#define WT_DOW  14286848ull
#define WT_DFF1 14811136ull
#define WT_DFF2 16908288ull
#define WT_OA1  19005440ull

static __device__ __forceinline__ float bu2f(unsigned int u){
  union{unsigned int i; float f;} x; x.i = u<<16; return x.f;
}
static __device__ __forceinline__ unsigned short f2bu(float f){
  union{bf16 h; unsigned short u;} x; x.h = __float2bfloat16(f); return x.u;
}

// ---------------- misc kernels ----------------
__global__ void k_maskmode(const unsigned char* __restrict__ m, int* __restrict__ flag){
  __shared__ int sh[256];
  int loc = 0;
  for(int i=threadIdx.x; i<ROWS_E; i+=256)
    if((i&3)!=0 && m[i]) loc = 1;
  sh[threadIdx.x] = loc;
  __syncthreads();
  if(threadIdx.x==0){
    int a=0;
    for(int j=0;j<256;j++) a |= sh[j];
    *flag = a;
  }
}

__global__ void k_real(const unsigned char* __restrict__ m, const int* __restrict__ flag,
                       float* __restrict__ real){
  int i = blockIdx.x*256 + threadIdx.x;
  if(i >= ROWS_E) return;
  int v = (*flag) ? (int)m[i] : ((const int*)m)[i];
  real[i] = v ? 0.f : 1.f;
}

__global__ void k_wsfail(float* __restrict__ out, float code){
  if(threadIdx.x==0) out[0] = code;
}

// weight transpose+convert: src fp32 [L][K][N] -> dst bf16 [L][N][K]
__global__ __launch_bounds__(256) void k_wt(const float* __restrict__ src,
    bf16* __restrict__ dst, int K, int N){
  __shared__ float t[32][33];
  const float* s = src + (size_t)blockIdx.z*K*N;
  bf16* d = dst + (size_t)blockIdx.z*K*N;
  int n0 = blockIdx.x*32, k0 = blockIdx.y*32;
  int tx = threadIdx.x & 31, ty = threadIdx.x >> 5;
  #pragma unroll
  for(int kk=0;kk<32;kk+=8)
    t[kk+ty][tx] = s[(size_t)(k0+kk+ty)*N + n0+tx];
  __syncthreads();
  #pragma unroll
  for(int nn=0;nn<32;nn+=8)
    d[(size_t)(n0+nn+ty)*K + k0+tx] = __float2bfloat16(t[tx][nn+ty]);
}

__global__ void k_embed(const float* __restrict__ atom, const float* __restrict__ W,
                        float* __restrict__ h){
  int idx = blockIdx.x*256 + threadIdx.x;
  if(idx >= ROWS_E*HGDIM) return;
  int row = idx >> 9, c = idx & 511;
  float s = 0.f;
  #pragma unroll
  for(int a=0;a<16;a++) s += atom[row*16+a] * W[a*HGDIM+c];
  h[idx] = s;
}

// LN wave-per-row: fp32 in -> bf16 out. D in {256,512}. 4 rows/block.
__global__ __launch_bounds__(256) void k_ln4(const float* __restrict__ x,
    const float* __restrict__ g, const float* __restrict__ bta,
    bf16* __restrict__ y, int D){
  int row = blockIdx.x*4 + (threadIdx.x>>6);
  int lane = threadIdx.x & 63;
  const float* xr = x + (size_t)row*D;
  int nch = D >> 8;
  float4 v[2];
  float s=0.f, s2=0.f;
  for(int j=0;j<nch;j++){
    v[j] = *(const float4*)&xr[j*256 + lane*4];
    s  += v[j].x+v[j].y+v[j].z+v[j].w;
    s2 += v[j].x*v[j].x+v[j].y*v[j].y+v[j].z*v[j].z+v[j].w*v[j].w;
  }
  #pragma unroll
  for(int o=32;o>0;o>>=1){ s += __shfl_xor(s,o); s2 += __shfl_xor(s2,o); }
  float mean = s / D;
  float var  = fmaxf(s2 / D - mean*mean, 0.f);
  float inv  = rsqrtf(var + 1e-5f);
  for(int j=0;j<nch;j++){
    int c = j*256 + lane*4;
    ushort4 o4;
    o4.x = f2bu((v[j].x-mean)*inv*g[c]   + bta[c]);
    o4.y = f2bu((v[j].y-mean)*inv*g[c+1] + bta[c+1]);
    o4.z = f2bu((v[j].z-mean)*inv*g[c+2] + bta[c+2]);
    o4.w = f2bu((v[j].w-mean)*inv*g[c+3] + bta[c+3]);
    *(ushort4*)&y[(size_t)row*D + c] = o4;
  }
}

// LN wave-per-row: bf16 in -> bf16 out
__global__ __launch_bounds__(256) void k_ln4b(const bf16* __restrict__ x,
    const float* __restrict__ g, const float* __restrict__ bta,
    bf16* __restrict__ y, int D){
  int row = blockIdx.x*4 + (threadIdx.x>>6);
  int lane = threadIdx.x & 63;
  const unsigned short* xr = (const unsigned short*)(x + (size_t)row*D);
  int nch = D >> 8;
  float4 v[2];
  float s=0.f, s2=0.f;
  for(int j=0;j<nch;j++){
    ushort4 u = *(const ushort4*)&xr[j*256 + lane*4];
    v[j].x = bu2f(u.x); v[j].y = bu2f(u.y); v[j].z = bu2f(u.z); v[j].w = bu2f(u.w);
    s  += v[j].x+v[j].y+v[j].z+v[j].w;
    s2 += v[j].x*v[j].x+v[j].y*v[j].y+v[j].z*v[j].z+v[j].w*v[j].w;
  }
  #pragma unroll
  for(int o=32;o>0;o>>=1){ s += __shfl_xor(s,o); s2 += __shfl_xor(s2,o); }
  float mean = s / D;
  float var  = fmaxf(s2 / D - mean*mean, 0.f);
  float inv  = rsqrtf(var + 1e-5f);
  for(int j=0;j<nch;j++){
    int c = j*256 + lane*4;
    ushort4 o4;
    o4.x = f2bu((v[j].x-mean)*inv*g[c]   + bta[c]);
    o4.y = f2bu((v[j].y-mean)*inv*g[c+1] + bta[c+1]);
    o4.z = f2bu((v[j].z-mean)*inv*g[c+2] + bta[c+2]);
    o4.w = f2bu((v[j].w-mean)*inv*g[c+3] + bta[c+3]);
    *(ushort4*)&y[(size_t)row*D + c] = o4;
  }
}

// rbf attention bias for one encoder block
__global__ void k_db(const float* __restrict__ coord, const float* __restrict__ real,
                     const float* __restrict__ rbfw, float* __restrict__ db){
  int idx = blockIdx.x*256 + threadIdx.x;
  if(idx >= NBATCH*SENC*SENC) return;
  int b = idx/(SENC*SENC), r = idx%(SENC*SENC), q = r/SENC, k = r%SENC;
  float out[NHEAD];
  bool masked = (real[b*NATOM+k]==0.f) || (k==q);
  if(masked){
    #pragma unroll
    for(int h=0;h<NHEAD;h++) out[h] = -1e9f;
  } else {
    float dx = coord[(b*NATOM+q)*3+0] - coord[(b*NATOM+k)*3+0];
    float dy = coord[(b*NATOM+q)*3+1] - coord[(b*NATOM+k)*3+1];
    float dz = coord[(b*NATOM+q)*3+2] - coord[(b*NATOM+k)*3+2];
    float d  = sqrtf(dx*dx+dy*dy+dz*dz + 1e-12f);
    #pragma unroll
    for(int h=0;h<NHEAD;h++) out[h]=0.f;
    for(int rr=0;rr<16;rr++){
      float cen = (10.f/15.f)*rr;
      float e = __expf(-2.f*(d-cen)*(d-cen));
      #pragma unroll
      for(int h=0;h<NHEAD;h++) out[h] += e * rbfw[rr*NHEAD+h];
    }
  }
  #pragma unroll
  for(int h=0;h<NHEAD;h++)
    db[(((size_t)b*NHEAD+h)*SENC + q)*SENC + k] = out[h];
}

// ===== shared MFMA macro =====
#define MFMA_(acc, a, bfr) acc = __builtin_amdgcn_mfma_f32_16x16x32_bf16(a, bfr, acc, 0, 0, 0);

// ===== encoder attention v3: MFMA flash, block=(b,h), 4 waves =====
#define EQKT(kt, acc) { \
  bf16x8 bklo = *(const bf16x8*)&Ks[(kt)*16 + l15][g*8]; \
  bf16x8 bkhi = *(const bf16x8*)&Ks[(kt)*16 + l15][32 + g*8]; \
  MFMA_(acc, aqlo, bklo) MFMA_(acc, aqhi, bkhi) }
#define EBIAS(kt, sv) { \
  const float* dbr = dbb + (qt*16 + g*4)*80 + l15 + 16*(kt); \
  sv[0] = sv[0]*0.125f + dbr[0]; \
  sv[1] = sv[1]*0.125f + dbr[80]; \
  sv[2] = sv[2]*0.125f + dbr[160]; \
  sv[3] = sv[3]*0.125f + dbr[240]; }
#define EMAXJ(j) fmaxf(fmaxf(fmaxf(s0[j],s1[j]),fmaxf(s2[j],s3[j])),s4[j])
#define EEXP(sv) { sv[0]=__expf(sv[0]-m0); sv[1]=__expf(sv[1]-m1); sv[2]=__expf(sv[2]-m2); sv[3]=__expf(sv[3]-m3); }
#define ESUMJ(j) (s0[j]+s1[j]+s2[j]+s3[j]+s4[j])
#define ESTP(kt, sv) { \
  Pw[w][g*4+0][l15+16*(kt)] = f2bu(sv[0]); \
  Pw[w][g*4+1][l15+16*(kt)] = f2bu(sv[1]); \
  Pw[w][g*4+2][l15+16*(kt)] = f2bu(sv[2]); \
  Pw[w][g*4+3][l15+16*(kt)] = f2bu(sv[3]); }
#define EST(ov, ct) { \
  ob[0*HGDIM + (ct)*16 + l15] = __float2bfloat16(ov[0]*i0); \
  ob[1*HGDIM + (ct)*16 + l15] = __float2bfloat16(ov[1]*i1); \
  ob[2*HGDIM + (ct)*16 + l15] = __float2bfloat16(ov[2]*i2); \
  ob[3*HGDIM + (ct)*16 + l15] = __float2bfloat16(ov[3]*i3); }

__global__ __launch_bounds__(256) void k_attn_enc3(
    const bf16* __restrict__ qkvb, const float* __restrict__ db,
    bf16* __restrict__ o_out)
{
  __shared__ unsigned short Qs[80][72];
  __shared__ unsigned short Ks[80][72];
  __shared__ unsigned short Vt[64][104];
  __shared__ unsigned short Pw[4][16][104];
  int bh = blockIdx.x; int h = bh & 7, b = bh >> 3;
  const bf16* base = qkvb + (size_t)b*SENC*1536;
  const float* dbb = db + (size_t)bh*6400;
  int tid = threadIdx.x;
  int w = tid >> 6, lane = tid & 63;
  int l15 = lane & 15, g = lane >> 4;
  for(int c = tid; c < 640; c += 256){
    int r = c >> 3, p = c & 7;
    *(uint4*)&Qs[r][p*8] = *(const uint4*)(base + (size_t)r*1536 + h*64 + p*8);
    *(uint4*)&Ks[r][p*8] = *(const uint4*)(base + (size_t)r*1536 + 512 + h*64 + p*8);
  }
  for(int c = tid; c < 80*64; c += 256){
    int k = c >> 6, d = c & 63;
    Vt[d][k] = *(const unsigned short*)(base + (size_t)k*1536 + 1024 + h*64 + d);
  }
  for(int c = tid; c < 64*16; c += 256){
    int d = c >> 4, cc = c & 15;
    Vt[d][80+cc] = 0;
  }
  {
    int r = lane >> 2, c4 = (lane & 3)*4;
    ushort4 zz = {0,0,0,0};
    *(ushort4*)&Pw[w][r][80 + c4] = zz;
  }
  __syncthreads();
  for(int qt = w; qt < 5; qt += 4){
    bf16x8 aqlo = *(const bf16x8*)&Qs[qt*16 + l15][g*8];
    bf16x8 aqhi = *(const bf16x8*)&Qs[qt*16 + l15][32 + g*8];
    f32x4 z = {0.f,0.f,0.f,0.f};
    f32x4 s0=z,s1=z,s2=z,s3=z,s4=z;
    EQKT(0,s0) EQKT(1,s1) EQKT(2,s2) EQKT(3,s3) EQKT(4,s4)
    EBIAS(0,s0) EBIAS(1,s1) EBIAS(2,s2) EBIAS(3,s3) EBIAS(4,s4)
    float m0=EMAXJ(0), m1=EMAXJ(1), m2=EMAXJ(2), m3=EMAXJ(3);
    #pragma unroll
    for(int off=1; off<16; off<<=1){
      m0 = fmaxf(m0, __shfl_xor(m0, off));
      m1 = fmaxf(m1, __shfl_xor(m1, off));
      m2 = fmaxf(m2, __shfl_xor(m2, off));
      m3 = fmaxf(m3, __shfl_xor(m3, off));
    }
    EEXP(s0) EEXP(s1) EEXP(s2) EEXP(s3) EEXP(s4)
    float l0=ESUMJ(0), l1=ESUMJ(1), l2=ESUMJ(2), l3=ESUMJ(3);
    #pragma unroll
    for(int off=1; off<16; off<<=1){
      l0 += __shfl_xor(l0, off);
      l1 += __shfl_xor(l1, off);
      l2 += __shfl_xor(l2, off);
      l3 += __shfl_xor(l3, off);
    }
    ESTP(0,s0) ESTP(1,s1) ESTP(2,s2) ESTP(3,s3) ESTP(4,s4)
    f32x4 o0=z, o1=z, o2=z, o3=z;
    #pragma unroll
    for(int kc=0; kc<3; kc++){
      bf16x8 ap = *(const bf16x8*)&Pw[w][l15][kc*32 + g*8];
      bf16x8 v0 = *(const bf16x8*)&Vt[l15][kc*32 + g*8];
      bf16x8 v1 = *(const bf16x8*)&Vt[16 + l15][kc*32 + g*8];
      bf16x8 v2 = *(const bf16x8*)&Vt[32 + l15][kc*32 + g*8];
      bf16x8 v3 = *(const bf16x8*)&Vt[48 + l15][kc*32 + g*8];
      MFMA_(o0, ap, v0) MFMA_(o1, ap, v1) MFMA_(o2, ap, v2) MFMA_(o3, ap, v3)
    }
    float i0 = 1.f/l0, i1 = 1.f/l1, i2 = 1.f/l2, i3 = 1.f/l3;
    bf16* ob = o_out + ((size_t)(b*SENC + qt*16 + g*4))*HGDIM + h*64;
    EST(o0, 0) EST(o1, 1) EST(o2, 2) EST(o3, 3)
  }
}

// ===== decoder attention v5: MFMA flash attention, block=(b,h), 4 waves =====
#define QKT(kt, acc) { bf16x8 bk = *(const bf16x8*)&Ks[(kt)*16 + l15][g*8]; MFMA_(acc, aq, bk) }
#define SMSC(sv, mbv) { sv[0]=sv[0]*SCAL+(mbv); sv[1]=sv[1]*SCAL+(mbv); sv[2]=sv[2]*SCAL+(mbv); sv[3]=sv[3]*SCAL+(mbv); }
#define MAXJ(j) fmaxf(fmaxf(fmaxf(fmaxf(s0[j],s1[j]),fmaxf(s2[j],s3[j])),fmaxf(fmaxf(s4[j],s5[j]),fmaxf(s6[j],s7[j]))),fmaxf(s8[j],s9[j]))
#define EXPS(sv) { sv[0]=__expf(sv[0]-m0); sv[1]=__expf(sv[1]-m1); sv[2]=__expf(sv[2]-m2); sv[3]=__expf(sv[3]-m3); }
#define SUMJ(j) (s0[j]+s1[j]+s2[j]+s3[j]+s4[j]+s5[j]+s6[j]+s7[j]+s8[j]+s9[j])
#define STP(kt, sv) { \
  Pw[w][g*4+0][l15+16*(kt)] = f2bu(sv[0]); \
  Pw[w][g*4+1][l15+16*(kt)] = f2bu(sv[1]); \
  Pw[w][g*4+2][l15+16*(kt)] = f2bu(sv[2]); \
  Pw[w][g*4+3][l15+16*(kt)] = f2bu(sv[3]); }

__global__ __launch_bounds__(256) void k_attn_dec5(
    const bf16* __restrict__ qkvb, const float* __restrict__ real,
    bf16* __restrict__ o_out)
{
  __shared__ unsigned short Qs[160][40];
  __shared__ unsigned short Ks[160][40];
  __shared__ unsigned short Vt[32][168];
  __shared__ unsigned short Pw[4][16][168];
  __shared__ float mb[160];
  const float SCAL = 0.17677669529663689f;
  int bh = blockIdx.x; int h = bh & 7, b = bh >> 3;
  const bf16* base = qkvb + (size_t)b*SDEC*768;
  int tid = threadIdx.x;
  int w = tid >> 6, lane = tid & 63;
  int l15 = lane & 15, g = lane >> 4;
  for(int c = tid; c < 160*4; c += 256){
    int r = c >> 2, p = c & 3;
    *(uint4*)&Qs[r][p*8] = *(const uint4*)(base + (size_t)r*768 + h*32 + p*8);
    *(uint4*)&Ks[r][p*8] = *(const uint4*)(base + (size_t)r*768 + 256 + h*32 + p*8);
  }
  for(int c = tid; c < 160*32; c += 256){
    int k = c >> 5, d = c & 31;
    Vt[d][k] = *(const unsigned short*)(base + (size_t)k*768 + 512 + h*32 + d);
  }
  for(int k = tid; k < 160; k += 256){
    int kk = (k<80)?k:k-80;
    mb[k] = (real[b*NATOM+kk]==0.f) ? -1e9f : 0.f;
  }
  __syncthreads();
  float mb0=mb[l15],     mb1=mb[l15+16],  mb2=mb[l15+32],  mb3=mb[l15+48],  mb4=mb[l15+64];
  float mb5=mb[l15+80],  mb6=mb[l15+96],  mb7=mb[l15+112], mb8=mb[l15+128], mb9=mb[l15+144];
  for(int qt = w; qt < 10; qt += 4){
    bf16x8 aq = *(const bf16x8*)&Qs[qt*16 + l15][g*8];
    f32x4 z = {0.f,0.f,0.f,0.f};
    f32x4 s0=z,s1=z,s2=z,s3=z,s4=z,s5=z,s6=z,s7=z,s8=z,s9=z;
    QKT(0,s0) QKT(1,s1) QKT(2,s2) QKT(3,s3) QKT(4,s4)
    QKT(5,s5) QKT(6,s6) QKT(7,s7) QKT(8,s8) QKT(9,s9)
    SMSC(s0,mb0) SMSC(s1,mb1) SMSC(s2,mb2) SMSC(s3,mb3) SMSC(s4,mb4)
    SMSC(s5,mb5) SMSC(s6,mb6) SMSC(s7,mb7) SMSC(s8,mb8) SMSC(s9,mb9)
    float m0=MAXJ(0), m1=MAXJ(1), m2=MAXJ(2), m3=MAXJ(3);
    #pragma unroll
    for(int off=1; off<16; off<<=1){
      m0 = fmaxf(m0, __shfl_xor(m0, off));
      m1 = fmaxf(m1, __shfl_xor(m1, off));
      m2 = fmaxf(m2, __shfl_xor(m2, off));
      m3 = fmaxf(m3, __shfl_xor(m3, off));
    }
    EXPS(s0) EXPS(s1) EXPS(s2) EXPS(s3) EXPS(s4)
    EXPS(s5) EXPS(s6) EXPS(s7) EXPS(s8) EXPS(s9)
    float l0=SUMJ(0), l1=SUMJ(1), l2=SUMJ(2), l3=SUMJ(3);
    #pragma unroll
    for(int off=1; off<16; off<<=1){
      l0 += __shfl_xor(l0, off);
      l1 += __shfl_xor(l1, off);
      l2 += __shfl_xor(l2, off);
      l3 += __shfl_xor(l3, off);
    }
    STP(0,s0) STP(1,s1) STP(2,s2) STP(3,s3) STP(4,s4)
    STP(5,s5) STP(6,s6) STP(7,s7) STP(8,s8) STP(9,s9)
    f32x4 o0 = z, o1 = z;
    #pragma unroll
    for(int kt=0; kt<5; kt++){
      bf16x8 ap = *(const bf16x8*)&Pw[w][l15][kt*32 + g*8];
      bf16x8 v0 = *(const bf16x8*)&Vt[l15][kt*32 + g*8];
      bf16x8 v1 = *(const bf16x8*)&Vt[16 + l15][kt*32 + g*8];
      MFMA_(o0, ap, v0)
      MFMA_(o1, ap, v1)
    }
    float i0 = 1.f/l0, i1 = 1.f/l1, i2 = 1.f/l2, i3 = 1.f/l3;
    bf16* ob = o_out + ((size_t)(b*SDEC + qt*16 + g*4))*HIDDIM + h*32;
    ob[0*HIDDIM + l15]      = __float2bfloat16(o0[0]*i0);
    ob[1*HIDDIM + l15]      = __float2bfloat16(o0[1]*i1);
    ob[2*HIDDIM + l15]      = __float2bfloat16(o0[2]*i2);
    ob[3*HIDDIM + l15]      = __float2bfloat16(o0[3]*i3);
    ob[0*HIDDIM + 16 + l15] = __float2bfloat16(o1[0]*i0);
    ob[1*HIDDIM + 16 + l15] = __float2bfloat16(o1[1]*i1);
    ob[2*HIDDIM + 16 + l15] = __float2bfloat16(o1[2]*i2);
    ob[3*HIDDIM + 16 + l15] = __float2bfloat16(o1[3]*i3);
  }
}

// ===== MFMA bf16 GEMM v7: 128x128, BK=64, 3-bit swizzle, prefetch, XCD remap =====
#define MFM(accv, av, bv) accv = __builtin_amdgcn_mfma_f32_16x16x32_bf16(av, bv, accv, 0, 0, 0);
#define EPIM(accv, rr, cc) { \
  int col = col0 + (cc)*16 + l15; \
  float bi = bias ? bias[col] : 0.f; \
  _Pragma("unroll") \
  for(int j=0;j<4;j++){ \
    int row = row0 + w*32 + (rr)*16 + g*4 + j; \
    float v = accv[j] + bi; \
    if(resid) v += resid[(size_t)row*Nw + col]; \
    if(act==1) v = v/(1.f+__expf(-v)); \
    if(Cf) Cf[(size_t)row*Nw + col] = v; \
    else   Cb[(size_t)row*Nw + col] = __float2bfloat16(v); } }

#define SUBSTEP(s) { \
  int ch = ((s)*4 + g) ^ sw7; \
  bf16x8 a0 = *(const bf16x8*)&As4[w*32 + l15][ch]; \
  bf16x8 a1 = *(const bf16x8*)&As4[w*32 + 16 + l15][ch]; \
  bf16x8 b0 = *(const bf16x8*)&Bs4[l15][ch]; \
  bf16x8 b1 = *(const bf16x8*)&Bs4[16 + l15][ch]; \
  bf16x8 b2 = *(const bf16x8*)&Bs4[32 + l15][ch]; \
  bf16x8 b3 = *(const bf16x8*)&Bs4[48 + l15][ch]; \
  bf16x8 b4 = *(const bf16x8*)&Bs4[64 + l15][ch]; \
  bf16x8 b5 = *(const bf16x8*)&Bs4[80 + l15][ch]; \
  bf16x8 b6 = *(const bf16x8*)&Bs4[96 + l15][ch]; \
  bf16x8 b7 = *(const bf16x8*)&Bs4[112 + l15][ch]; \
  MFM(c00, a0, b0) MFM(c01, a0, b1) MFM(c02, a0, b2) MFM(c03, a0, b3) \
  MFM(c04, a0, b4) MFM(c05, a0, b5) MFM(c06, a0, b6) MFM(c07, a0, b7) \
  MFM(c10, a1, b0) MFM(c11, a1, b1) MFM(c12, a1, b2) MFM(c13, a1, b3) \
  MFM(c14, a1, b4) MFM(c15, a1, b5) MFM(c16, a1, b6) MFM(c17, a1, b7) }

__global__ __launch_bounds__(256) void k_gemm_mfma7(
    const bf16* __restrict__ A, const bf16* __restrict__ WT,
    const float* __restrict__ bias, const float* __restrict__ resid,
    float* __restrict__ Cf, bf16* __restrict__ Cb,
    int M, int K, int Nw, int act)
{
  __shared__ uint4 As4[128][8];
  __shared__ uint4 Bs4[128][8];
  int tid = threadIdx.x;
  int w = tid >> 6, lane = tid & 63;
  int l15 = lane & 15, g = lane >> 4;
  int lin = blockIdx.x + gridDim.x*blockIdx.y;
  int bcol = lin / gridDim.y;
  int brw  = lin - bcol*gridDim.y;
  int row0 = brw*128, col0 = bcol*128;
  int arow = tid >> 1, ahalf = tid & 1;
  int swr = arow & 7;
  int sw7 = l15 & 7;
  int bb = ahalf*4;
  const bf16* aP = A  + (size_t)(row0+arow)*K + ahalf*32;
  const bf16* bP = WT + (size_t)(col0+arow)*K + ahalf*32;
  f32x4 z = {0.f,0.f,0.f,0.f};
  f32x4 c00=z,c01=z,c02=z,c03=z,c04=z,c05=z,c06=z,c07=z;
  f32x4 c10=z,c11=z,c12=z,c13=z,c14=z,c15=z,c16=z,c17=z;
  uint4 av0,av1,av2,av3,bv0,bv1,bv2,bv3;
  {
    const uint4* asrc = (const uint4*)aP;
    const uint4* bsrc = (const uint4*)bP;
    av0=asrc[0]; av1=asrc[1]; av2=asrc[2]; av3=asrc[3];
    bv0=bsrc[0]; bv1=bsrc[1]; bv2=bsrc[2]; bv3=bsrc[3];
  }
  for(int k0=0;k0<K;k0+=64){
    As4[arow][(bb+0)^swr] = av0;
    As4[arow][(bb+1)^swr] = av1;
    As4[arow][(bb+2)^swr] = av2;
    As4[arow][(bb+3)^swr] = av3;
    Bs4[arow][(bb+0)^swr] = bv0;
    Bs4[arow][(bb+1)^swr] = bv1;
    Bs4[arow][(bb+2)^swr] = bv2;
    Bs4[arow][(bb+3)^swr] = bv3;
    __syncthreads();
    int kn = k0 + 64;
    if(kn < K){
      const uint4* asrc = (const uint4*)(aP + kn);
      const uint4* bsrc = (const uint4*)(bP + kn);
      av0=asrc[0]; av1=asrc[1]; av2=asrc[2]; av3=asrc[3];
      bv0=bsrc[0]; bv1=bsrc[1]; bv2=bsrc[2]; bv3=bsrc[3];
    }
    SUBSTEP(0)
    SUBSTEP(1)
    __syncthreads();
  }
  EPIM(c00, 0, 0) EPIM(c01, 0, 1) EPIM(c02, 0, 2) EPIM(c03, 0, 3)
  EPIM(c04, 0, 4) EPIM(c05, 0, 5) EPIM(c06, 0, 6) EPIM(c07, 0, 7)
  EPIM(c10, 1, 0) EPIM(c11, 1, 1) EPIM(c12, 1, 2) EPIM(c13, 1, 3)
  EPIM(c14, 1, 4) EPIM(c15, 1, 5) EPIM(c16, 1, 6) EPIM(c17, 1, 7)
}

// ===== MFMA bf16 GEMM v10: 64x128, BK=64, depth-2 register prefetch =====
#define EPIM8(accv, rr, cc) { \
  int col = col0 + w*32 + (cc)*16 + l15; \
  float bi = bias ? bias[col] : 0.f; \
  _Pragma("unroll") \
  for(int j=0;j<4;j++){ \
    int row = row0 + (rr)*16 + g*4 + j; \
    float v = accv[j] + bi; \
    if(resid) v += resid[(size_t)row*Nw + col]; \
    if(act==1) v = v/(1.f+__expf(-v)); \
    if(Cf) Cf[(size_t)row*Nw + col] = v; \
    else   Cb[(size_t)row*Nw + col] = __float2bfloat16(v); } }

#define SUBSTEP8(s) { \
  int ch = ((s)*4 + g) ^ sw7; \
  bf16x8 a0 = *(const bf16x8*)&As4[l15][ch]; \
  bf16x8 a1 = *(const bf16x8*)&As4[16 + l15][ch]; \
  bf16x8 a2 = *(const bf16x8*)&As4[32 + l15][ch]; \
  bf16x8 a3 = *(const bf16x8*)&As4[48 + l15][ch]; \
  bf16x8 b0 = *(const bf16x8*)&Bs4[w*32 + l15][ch]; \
  bf16x8 b1 = *(const bf16x8*)&Bs4[w*32 + 16 + l15][ch]; \
  MFM(c00, a0, b0) MFM(c01, a0, b1) \
  MFM(c10, a1, b0) MFM(c11, a1, b1) \
  MFM(c20, a2, b0) MFM(c21, a2, b1) \
  MFM(c30, a3, b0) MFM(c31, a3, b1) }

#define LOADSET(aw0, aw1, bw0, bw1, bw2, bw3, koff) { \
  const uint4* asrc = (const uint4*)(aP + (koff)); \
  const uint4* bsrc = (const uint4*)(bP + (koff)); \
  aw0=asrc[0]; aw1=asrc[1]; \
  bw0=bsrc[0]; bw1=bsrc[1]; bw2=bsrc[2]; bw3=bsrc[3]; }

#define STORESET(aw0, aw1, bw0, bw1, bw2, bw3) { \
  As4[arow4][(2*aq+0)^swA] = aw0; \
  As4[arow4][(2*aq+1)^swA] = aw1; \
  Bs4[brow][(bbp+0)^swB] = bw0; \
  Bs4[brow][(bbp+1)^swB] = bw1; \
  Bs4[brow][(bbp+2)^swB] = bw2; \
  Bs4[brow][(bbp+3)^swB] = bw3; }

__global__ __launch_bounds__(256) void k_gemm_mfma10(
    const bf16* __restrict__ A, const bf16* __restrict__ WT,
    const float* __restrict__ bias, const float* __restrict__ resid,
    float* __restrict__ Cf, bf16* __restrict__ Cb,
    int M, int K, int Nw, int act)
{
  __shared__ uint4 As4[64][8];
  __shared__ uint4 Bs4[128][8];
  int tid = threadIdx.x;
  int w = tid >> 6, lane = tid & 63;
  int l15 = lane & 15, g = lane >> 4;
  int lin = blockIdx.x + gridDim.x*blockIdx.y;
  int bcol = lin / gridDim.y;
  int brw  = lin - bcol*gridDim.y;
  int row0 = brw*64, col0 = bcol*128;
  int arow4 = tid >> 2, aq = tid & 3;
  int swA = arow4 & 7;
  int brow = tid >> 1, bhalf = tid & 1;
  int swB = brow & 7;
  int sw7 = l15 & 7;
  int bbp = bhalf*4;
  const bf16* aP = A  + (size_t)(row0+arow4)*K + aq*16;
  const bf16* bP = WT + (size_t)(col0+brow)*K + bhalf*32;
  f32x4 z = {0.f,0.f,0.f,0.f};
  f32x4 c00=z,c01=z,c10=z,c11=z,c20=z,c21=z,c30=z,c31=z;
  uint4 aA0,aA1,bA0,bA1,bA2,bA3;
  uint4 aB0,aB1,bB0,bB1,bB2,bB3;
  LOADSET(aA0,aA1,bA0,bA1,bA2,bA3, 0)
  LOADSET(aB0,aB1,bB0,bB1,bB2,bB3, 64)
  for(int k0=0;k0<K;k0+=128){
    STORESET(aA0,aA1,bA0,bA1,bA2,bA3)
    __syncthreads();
    if(k0+128 < K){ LOADSET(aA0,aA1,bA0,bA1,bA2,bA3, k0+128) }
    SUBSTEP8(0)
    SUBSTEP8(1)
    __syncthreads();
    STORESET(aB0,aB1,bB0,bB1,bB2,bB3)
    __syncthreads();
    if(k0+192 < K){ LOADSET(aB0,aB1,bB0,bB1,bB2,bB3, k0+192) }
    SUBSTEP8(0)
    SUBSTEP8(1)
    __syncthreads();
  }
  EPIM8(c00, 0, 0) EPIM8(c01, 0, 1)
  EPIM8(c10, 1, 0) EPIM8(c11, 1, 1)
  EPIM8(c20, 2, 0) EPIM8(c21, 2, 1)
  EPIM8(c30, 3, 0) EPIM8(c31, 3, 1)
}

// ===== MFMA bf16 GEMM v11: 64x64 tile, BK=64, high occupancy for small-N GEMMs =====
#define EPIM11(accv, rr) { \
  int col = col0 + w*16 + l15; \
  float bi = bias ? bias[col] : 0.f; \
  _Pragma("unroll") \
  for(int j=0;j<4;j++){ \
    int row = row0 + (rr)*16 + g*4 + j; \
    float v = accv[j] + bi; \
    if(resid) v += resid[(size_t)row*Nw + col]; \
    if(act==1) v = v/(1.f+__expf(-v)); \
    if(Cf) Cf[(size_t)row*Nw + col] = v; \
    else   Cb[(size_t)row*Nw + col] = __float2bfloat16(v); } }

#define SUBSTEP11(s) { \
  int ch = ((s)*4 + g) ^ sw7; \
  bf16x8 a0 = *(const bf16x8*)&As4[l15][ch]; \
  bf16x8 a1 = *(const bf16x8*)&As4[16 + l15][ch]; \
  bf16x8 a2 = *(const bf16x8*)&As4[32 + l15][ch]; \
  bf16x8 a3 = *(const bf16x8*)&As4[48 + l15][ch]; \
  bf16x8 b0 = *(const bf16x8*)&Bs4[w*16 + l15][ch]; \
  MFM(c0, a0, b0) MFM(c1, a1, b0) MFM(c2, a2, b0) MFM(c3, a3, b0) }

__global__ __launch_bounds__(256) void k_gemm_mfma11(
    const bf16* __restrict__ A, const bf16* __restrict__ WT,
    const float* __restrict__ bias, const float* __restrict__ resid,
    float* __restrict__ Cf, bf16* __restrict__ Cb,
    int M, int K, int Nw, int act)
{
  __shared__ uint4 As4[64][8];
  __shared__ uint4 Bs4[64][8];
  int tid = threadIdx.x;
  int w = tid >> 6, lane = tid & 63;
  int l15 = lane & 15, g = lane >> 4;
  int lin = blockIdx.x + gridDim.x*blockIdx.y;
  int bcol = lin / gridDim.y;
  int brw  = lin - bcol*gridDim.y;
  int row0 = brw*64, col0 = bcol*64;
  int arow = tid >> 2, apair = (tid & 3)*2;
  int swr = arow & 7;
  int sw7 = l15 & 7;
  const bf16* aP = A  + (size_t)(row0+arow)*K + apair*8;
  const bf16* bP = WT + (size_t)(col0+arow)*K + apair*8;
  f32x4 z = {0.f,0.f,0.f,0.f};
  f32x4 c0=z,c1=z,c2=z,c3=z;
  uint4 av0,av1,bv0,bv1;
  {
    const uint4* asrc = (const uint4*)aP;
    const uint4* bsrc = (const uint4*)bP;
    av0=asrc[0]; av1=asrc[1];
    bv0=bsrc[0]; bv1=bsrc[1];
  }
  for(int k0=0;k0<K;k0+=64){
    As4[arow][(apair+0)^swr] = av0;
    As4[arow][(apair+1)^swr] = av1;
    Bs4[arow][(apair+0)^swr] = bv0;
    Bs4[arow][(apair+1)^swr] = bv1;
    __syncthreads();
    int kn = k0 + 64;
    if(kn < K){
      const uint4* asrc = (const uint4*)(aP + kn);
      const uint4* bsrc = (const uint4*)(bP + kn);
      av0=asrc[0]; av1=asrc[1];
      bv0=bsrc[0]; bv1=bsrc[1];
    }
    SUBSTEP11(0)
    SUBSTEP11(1)
    __syncthreads();
  }
  EPIM11(c0, 0) EPIM11(c1, 1) EPIM11(c2, 2) EPIM11(c3, 3)
}

// ===== tiny-N GEMM: 16 rows/block, A tile + W staged in LDS, K=256, Nw<=16 =====
__global__ __launch_bounds__(256) void k_gemm_tiny(
    const bf16* __restrict__ A, const float* __restrict__ W,
    const float* __restrict__ bias, float* __restrict__ C,
    int Nw, int act)
{
  __shared__ unsigned short As[16][264];
  __shared__ float Ws[4096];
  int tid = threadIdx.x;
  int row0 = blockIdx.x*16;
  int ar = tid >> 4, ac = (tid & 15) * 16;
  const uint4* asrc = (const uint4*)(A + (size_t)(row0+ar)*256 + ac);
  *(uint4*)&As[ar][ac]   = asrc[0];
  *(uint4*)&As[ar][ac+8] = asrc[1];
  int wtot = 256*Nw;
  for(int i=tid; i<wtot; i+=256) Ws[i] = W[i];
  __syncthreads();
  int row = tid >> 4, col = tid & 15;
  if(col < Nw){
    float acc = bias ? bias[col] : 0.f;
    #pragma unroll 8
    for(int k=0;k<256;k++)
      acc += bu2f(As[row][k]) * Ws[k*Nw+col];
    if(act==1) acc = acc/(1.f+__expf(-acc));
    C[(size_t)(row0+row)*Nw + col] = acc;
  }
}

__global__ __launch_bounds__(256) void k_kl(const float* __restrict__ mom,
    const float* __restrict__ real, float* __restrict__ part){
  int i = blockIdx.x*256 + threadIdx.x;
  float s = 0.f;
  if(i < ROWS_E){
    const float* m = mom + (size_t)i*12;
    float acc = 0.f;
    #pragma unroll
    for(int d=0;d<6;d++){ float mu=m[d], lv=m[6+d]; acc += 1.f + lv - mu*mu - expf(lv); }
    s = acc * real[i];
  }
  #pragma unroll
  for(int o=32;o>0;o>>=1) s += __shfl_xor(s,o);
  __shared__ float r[4];
  if((threadIdx.x&63)==0) r[threadIdx.x>>6]=s;
  __syncthreads();
  if(threadIdx.x==0) part[blockIdx.x] = r[0]+r[1]+r[2]+r[3];
}

__global__ void k_klfin(const float* __restrict__ part, float* __restrict__ o){
  float s=0.f;
  for(int i=0;i<40;i++) s += part[i];
  *o = -0.5f * (s/(float)ROWS_E) * 1e-6f;
}

// h*real -> bf16
__global__ void k_cvtrs(const float* __restrict__ h, const float* __restrict__ real,
                        bf16* __restrict__ o){
  int idx = blockIdx.x*256 + threadIdx.x;
  if(idx >= ROWS_E*HGDIM) return;
  int row = idx >> 9;
  o[idx] = __float2bfloat16(h[idx]*real[row]);
}

__global__ __launch_bounds__(256) void k_build_x(
  const float* __restrict__ coord_t, const float* __restrict__ atomics_t, const float* __restrict__ tin,
  const float* __restrict__ qout_w, const float* __restrict__ qout_b, const float* __restrict__ cond,
  const float* __restrict__ lin_w, const float* __restrict__ atom_emb,
  const float* __restrict__ mom, const float* __restrict__ real, float* __restrict__ x)
{
  int idx = blockIdx.x*256 + threadIdx.x;
  if(idx >= NBATCH*SDEC*HIDDIM) return;
  int c = idx & 255; int rowg = idx >> 8; int s = rowg % SDEC; int b = rowg / SDEC;
  int n = (s<NATOM)? s : s-NATOM;
  int j = c >> 1;
  float div = __expf(-(float)(2*j) * (9.210340371976184f/256.f));
  float ang = (float)n * div;
  float pe = (c & 1) ? __cosf(ang) : __sinf(ang);
  float rl = real[b*NATOM + n];
  float v;
  if(s < NATOM){
    int rown = b*NATOM + n;
    float cl = 0.f;
    #pragma unroll
    for(int a=0;a<3;a++) cl += coord_t[rown*3+a] * lin_w[a*HIDDIM+c];
    int bi=0; float bv = atomics_t[rown*16];
    for(int a=1;a<16;a++){ float vv=atomics_t[rown*16+a]; if(vv>bv){bv=vv; bi=a;} }
    float ae = atom_emb[bi*HIDDIM+c];
    float tb = tin[b];
    float tf;
    if(c < 128){
      float fr = __expf(-(float)c * (5.298317366548036f/128.f));
      tf = __sinf(tb*200.f*fr);
    } else {
      float fr = __expf(-(float)(c-128) * (5.298317366548036f/128.f));
      tf = __cosf(tb*200.f*fr);
    }
    v = (cl + ae + pe + tf)*rl + cond[c];
  } else {
    int rown = b*NATOM + n;
    const float* mp = mom + (size_t)rown*12;
    float s2 = qout_b[c];
    #pragma unroll
    for(int d=0;d<6;d++) s2 += mp[d]*qout_w[d*HIDDIM+c];
    v = (s2 + pe)*rl + cond[HIDDIM+c];
  }
  x[idx] = v;
}

// h_out -> bf16 only
__global__ void k_hout(const float* __restrict__ x, const float* __restrict__ real,
                       bf16* __restrict__ h_out_b){
  int idx = blockIdx.x*256 + threadIdx.x;
  if(idx >= ROWS_E*HIDDIM) return;
  int c = idx & 255, row = idx >> 8;
  int n = row % NATOM, b = row / NATOM;
  float v = x[((size_t)(b*SDEC+n))*HIDDIM + c] * real[row];
  h_out_b[idx] = __float2bfloat16(v);
}

// ---------------- launch ----------------
extern "C" void kernel_launch(void* const* d_in, const int* in_sizes, int n_in,
                              void* d_out, int out_size, void* d_ws, size_t ws_size,
                              hipStream_t stream){
  (void)in_sizes; (void)n_in; (void)out_size;
  const float* coord_ori   = (const float*)d_in[0];
  const float* atomics_ori = (const float*)d_in[1];
  const unsigned char* pmask = (const unsigned char*)d_in[2];
  const float* coord_t     = (const float*)d_in[3];
  const float* atomics_t   = (const float*)d_in[4];
  const float* t_in        = (const float*)d_in[5];
  const float* enc_embed_w = (const float*)d_in[6];
  const float* rbf_w       = (const float*)d_in[7];
  const float* e_qkv_w=(const float*)d_in[8];  const float* e_qkv_b=(const float*)d_in[9];
  const float* e_out_w=(const float*)d_in[10]; const float* e_out_b=(const float*)d_in[11];
  const float* e_ff1_w=(const float*)d_in[12]; const float* e_ff1_b=(const float*)d_in[13];
  const float* e_ff2_w=(const float*)d_in[14]; const float* e_ff2_b=(const float*)d_in[15];
  const float* e_ln1_g=(const float*)d_in[16]; const float* e_ln1_b=(const float*)d_in[17];
  const float* e_ln2_g=(const float*)d_in[18]; const float* e_ln2_b=(const float*)d_in[19];
  const float* enc_proj_w=(const float*)d_in[20];
  const float* quant_w=(const float*)d_in[21]; const float* quant_b=(const float*)d_in[22];
  const float* qout_w=(const float*)d_in[23];  const float* qout_b=(const float*)d_in[24];
  const float* cond_embed=(const float*)d_in[25];
  const float* lin_embed_w=(const float*)d_in[26];
  const float* atom_embed=(const float*)d_in[27];
  const float* d_qkv_w=(const float*)d_in[28]; const float* d_qkv_b=(const float*)d_in[29];
  const float* d_ow   =(const float*)d_in[30]; const float* d_ob   =(const float*)d_in[31];
  const float* d_ff1_w=(const float*)d_in[32]; const float* d_ff1_b=(const float*)d_in[33];
  const float* d_ff2_w=(const float*)d_in[34]; const float* d_ff2_b=(const float*)d_in[35];
  const float* d_ln1_g=(const float*)d_in[36]; const float* d_ln1_b=(const float*)d_in[37];
  const float* d_ln2_g=(const float*)d_in[38]; const float* d_ln2_b=(const float*)d_in[39];
  const float* oc_ln_g=(const float*)d_in[40]; const float* oc_ln_b=(const float*)d_in[41];
  const float* oc_w   =(const float*)d_in[42];
  const float* oa1_w  =(const float*)d_in[43]; const float* oa1_b=(const float*)d_in[44];
  const float* oa2_w  =(const float*)d_in[45]; const float* oa2_b=(const float*)d_in[46];

  float* ws   = (float*)d_ws;
  float* real = ws + OFF_REAL;
  int*   flag = (int*)(ws + OFF_FLAG);
  float* h    = ws + OFF_H;
  bf16*  qkvb = (bf16*)(ws + OFF_QKVB);
  float* db   = ws + OFF_DB;
  bf16*  lnb  = (bf16*)(ws + OFF_LNB);
  bf16*  aob  = (bf16*)(ws + OFF_AOB);
  bf16*  mid  = (bf16*)(ws + OFF_MID);
  float* mom  = ws + OFF_MOM;
  float* klp  = ws + OFF_KL;
  bf16*  wt   = (bf16*)(ws + OFF_WT);
  float* out  = (float*)d_out;

  if(ws_size < NEED_BYTES){
    k_wsfail<<<1,64,0,stream>>>(out, 1.0e6f + (float)(ws_size>>20));
    return;
  }

  // one-time weight transposes (fp32 [K][N] -> bf16 [N][K])
  k_wt<<<dim3(48,16,4),256,0,stream>>>(e_qkv_w,  wt+WT_EQKV, 512, 1536);
  k_wt<<<dim3(16,16,4),256,0,stream>>>(e_out_w,  wt+WT_EOUT, 512, 512);
  k_wt<<<dim3(64,16,4),256,0,stream>>>(e_ff1_w,  wt+WT_EFF1, 512, 2048);
  k_wt<<<dim3(16,64,4),256,0,stream>>>(e_ff2_w,  wt+WT_EFF2, 2048, 512);
  k_wt<<<dim3(8,16,1), 256,0,stream>>>(enc_proj_w, wt+WT_PROJ, 512, 256);
  k_wt<<<dim3(24,8,8), 256,0,stream>>>(d_qkv_w,  wt+WT_DQKV, 256, 768);
  k_wt<<<dim3(8,8,8),  256,0,stream>>>(d_ow,     wt+WT_DOW,  256, 256);
  k_wt<<<dim3(32,8,8), 256,0,stream>>>(d_ff1_w,  wt+WT_DFF1, 256, 1024);
  k_wt<<<dim3(8,32,8), 256,0,stream>>>(d_ff2_w,  wt+WT_DFF2, 1024, 256);
  k_wt<<<dim3(8,8,1),  256,0,stream>>>(oa1_w,    wt+WT_OA1,  256, 256);

  k_maskmode<<<1,256,0,stream>>>(pmask, flag);
  k_real <<<40,   256, 0, stream>>>(pmask, flag, real);
  k_embed<<<20480,256, 0, stream>>>(atomics_ori, enc_embed_w, h);

  // ===== encoder =====
  for(int i=0;i<4;i++){
    k_ln4<<<ROWS_E/4,256,0,stream>>>(h, e_ln1_g+i*HGDIM, e_ln1_b+i*HGDIM, lnb, HGDIM);
    k_gemm_mfma7<<<dim3(12,80),256,0,stream>>>(lnb, wt+WT_EQKV+(size_t)i*512*1536,
        e_qkv_b+i*3*HGDIM, nullptr, nullptr, qkvb, ROWS_E, HGDIM, 3*HGDIM, 0);
    k_db<<<3200,256,0,stream>>>(coord_ori, real, rbf_w + i*16*NHEAD, db);
    k_attn_enc3<<<NBATCH*NHEAD,256,0,stream>>>(qkvb, db, aob);
    k_gemm_mfma11<<<dim3(8,160),256,0,stream>>>(aob, wt+WT_EOUT+(size_t)i*512*512,
        e_out_b+i*HGDIM, h, h, nullptr, ROWS_E, HGDIM, HGDIM, 0);
    k_ln4<<<ROWS_E/4,256,0,stream>>>(h, e_ln2_g+i*HGDIM, e_ln2_b+i*HGDIM, lnb, HGDIM);
    k_gemm_mfma7<<<dim3(16,80),256,0,stream>>>(lnb, wt+WT_EFF1+(size_t)i*512*2048,
        e_ff1_b+i*4*HGDIM, nullptr, nullptr, mid, ROWS_E, HGDIM, 4*HGDIM, 1);
    k_gemm_mfma11<<<dim3(8,160),256,0,stream>>>(mid, wt+WT_EFF2+(size_t)i*2048*512,
        e_ff2_b+i*HGDIM, h, h, nullptr, ROWS_E, 4*HGDIM, HGDIM, 0);
  }

  k_cvtrs<<<20480,256,0,stream>>>(h, real, lnb);
  k_gemm_mfma11<<<dim3(4,160),256,0,stream>>>(lnb, wt+WT_PROJ,
      nullptr, nullptr, nullptr, aob, ROWS_E, HGDIM, HIDDIM, 0);
  k_gemm_tiny<<<640,256,0,stream>>>(aob, quant_w, quant_b, mom, 12, 0);
  k_kl   <<<40,256,0,stream>>>(mom, real, klp);
  k_klfin<<<1,1,0,stream>>>(klp, out + 194560);

  k_build_x<<<20480,256,0,stream>>>(coord_t, atomics_t, t_in, qout_w, qout_b,
      cond_embed, lin_embed_w, atom_embed, mom, real, h);

  // ===== decoder =====
  for(int i=0;i<8;i++){
    k_ln4<<<ROWS_D/4,256,0,stream>>>(h, d_ln1_g+i*HIDDIM, d_ln1_b+i*HIDDIM, lnb, HIDDIM);
    k_gemm_mfma10<<<dim3(6,320),256,0,stream>>>(lnb, wt+WT_DQKV+(size_t)i*256*768,
        d_qkv_b+i*3*HIDDIM, nullptr, nullptr, qkvb, ROWS_D, HIDDIM, 3*HIDDIM, 0);
    k_attn_dec5<<<NBATCH*NHEAD,256,0,stream>>>(qkvb, real, aob);
    k_gemm_mfma11<<<dim3(4,320),256,0,stream>>>(aob, wt+WT_DOW+(size_t)i*256*256,
        d_ob+i*HIDDIM, h, h, nullptr, ROWS_D, HIDDIM, HIDDIM, 0);
    k_ln4<<<ROWS_D/4,256,0,stream>>>(h, d_ln2_g+i*HIDDIM, d_ln2_b+i*HIDDIM, lnb, HIDDIM);
    k_gemm_mfma7<<<dim3(8,160),256,0,stream>>>(lnb, wt+WT_DFF1+(size_t)i*256*1024,
        d_ff1_b+i*4*HIDDIM, nullptr, nullptr, mid, ROWS_D, HIDDIM, 4*HIDDIM, 1);
    k_gemm_mfma11<<<dim3(4,320),256,0,stream>>>(mid, wt+WT_DFF2+(size_t)i*1024*256,
        d_ff2_b+i*HIDDIM, h, h, nullptr, ROWS_D, 4*HIDDIM, HIDDIM, 0);
  }

  // ===== heads =====
  k_hout<<<10240,256,0,stream>>>(h, real, aob);
  k_ln4b<<<ROWS_E/4,256,0,stream>>>(aob, oc_ln_g, oc_ln_b, lnb, HIDDIM);
  k_gemm_tiny<<<640,256,0,stream>>>(lnb, oc_w, nullptr, out, 3, 0);
  k_gemm_mfma11<<<dim3(4,160),256,0,stream>>>(aob, wt+WT_OA1, oa1_b, nullptr,
      nullptr, mid, ROWS_E, HIDDIM, HIDDIM, 1);
  k_gemm_tiny<<<640,256,0,stream>>>(mid, oa2_w, oa2_b, out + 30720, 16, 0);
}

// Round 24
// 2575.115 us; speedup vs baseline: 1.0620x; 1.0086x over previous
//
#include <hip/hip_runtime.h>
#include <hip/hip_bf16.h>
#include <math.h>

#define NBATCH 128
#define NATOM  80
#define SENC   80
#define SDEC   160
#define HGDIM  512
#define HIDDIM 256
#define NHEAD  8
#define ROWS_E (NBATCH*NATOM)   /* 10240 */
#define ROWS_D (NBATCH*SDEC)    /* 20480 */

typedef __hip_bfloat16 bf16;
typedef __attribute__((ext_vector_type(8))) short bf16x8;
typedef __attribute__((ext_vector_type(4))) float f32x4;

// ---------------- workspace layout (float units) ----------------
#define OFF_REAL 0ull
#define OFF_FLAG 10240ull
#define OFF_H    16384ull
#define OFF_QKVB (OFF_H   + 5242880ull)
#define OFF_DB   (OFF_QKVB+ 7864320ull)
#define OFF_LNB  (OFF_DB  + 6553600ull)
#define OFF_AOB  (OFF_LNB + 2621440ull)
#define OFF_MID  (OFF_AOB + 2621440ull)
#define OFF_MOM  (OFF_MID + 10485760ull)
#define OFF_KL   (OFF_MOM + 122880ull)
#define OFF_WT   (OFF_KL  + 64ull)
#define NEED_BYTES 184058112ull

// WT sub-offsets (bf16 element counts)
#define WT_EQKV 0ull
#define WT_EOUT 3145728ull
#define WT_EFF1 4194304ull
#define WT_EFF2 8388608ull
#define WT_PROJ 12582912ull
#define WT_DQKV 12713984ull
#define WT_DOW  14286848ull
#define WT_DFF1 14811136ull
#define WT_DFF2 16908288ull
#define WT_OA1  19005440ull

static __device__ __forceinline__ float bu2f(unsigned int u){
  union{unsigned int i; float f;} x; x.i = u<<16; return x.f;
}
static __device__ __forceinline__ unsigned short f2bu(float f){
  union{bf16 h; unsigned short u;} x; x.h = __float2bfloat16(f); return x.u;
}

// ---------------- misc kernels ----------------
__global__ void k_maskmode(const unsigned char* __restrict__ m, int* __restrict__ flag){
  __shared__ int sh[256];
  int loc = 0;
  for(int i=threadIdx.x; i<ROWS_E; i+=256)
    if((i&3)!=0 && m[i]) loc = 1;
  sh[threadIdx.x] = loc;
  __syncthreads();
  if(threadIdx.x==0){
    int a=0;
    for(int j=0;j<256;j++) a |= sh[j];
    *flag = a;
  }
}

__global__ void k_real(const unsigned char* __restrict__ m, const int* __restrict__ flag,
                       float* __restrict__ real){
  int i = blockIdx.x*256 + threadIdx.x;
  if(i >= ROWS_E) return;
  int v = (*flag) ? (int)m[i] : ((const int*)m)[i];
  real[i] = v ? 0.f : 1.f;
}

__global__ void k_wsfail(float* __restrict__ out, float code){
  if(threadIdx.x==0) out[0] = code;
}

// weight transpose+convert: src fp32 [L][K][N] -> dst bf16 [L][N][K]
__global__ __launch_bounds__(256) void k_wt(const float* __restrict__ src,
    bf16* __restrict__ dst, int K, int N){
  __shared__ float t[32][33];
  const float* s = src + (size_t)blockIdx.z*K*N;
  bf16* d = dst + (size_t)blockIdx.z*K*N;
  int n0 = blockIdx.x*32, k0 = blockIdx.y*32;
  int tx = threadIdx.x & 31, ty = threadIdx.x >> 5;
  #pragma unroll
  for(int kk=0;kk<32;kk+=8)
    t[kk+ty][tx] = s[(size_t)(k0+kk+ty)*N + n0+tx];
  __syncthreads();
  #pragma unroll
  for(int nn=0;nn<32;nn+=8)
    d[(size_t)(n0+nn+ty)*K + k0+tx] = __float2bfloat16(t[tx][nn+ty]);
}

__global__ void k_embed(const float* __restrict__ atom, const float* __restrict__ W,
                        float* __restrict__ h){
  int idx = blockIdx.x*256 + threadIdx.x;
  if(idx >= ROWS_E*HGDIM) return;
  int row = idx >> 9, c = idx & 511;
  float s = 0.f;
  #pragma unroll
  for(int a=0;a<16;a++) s += atom[row*16+a] * W[a*HGDIM+c];
  h[idx] = s;
}

// LN wave-per-row: fp32 in -> bf16 out. D in {256,512}. 4 rows/block.
__global__ __launch_bounds__(256) void k_ln4(const float* __restrict__ x,
    const float* __restrict__ g, const float* __restrict__ bta,
    bf16* __restrict__ y, int D){
  int row = blockIdx.x*4 + (threadIdx.x>>6);
  int lane = threadIdx.x & 63;
  const float* xr = x + (size_t)row*D;
  int nch = D >> 8;
  float4 v[2];
  float s=0.f, s2=0.f;
  for(int j=0;j<nch;j++){
    v[j] = *(const float4*)&xr[j*256 + lane*4];
    s  += v[j].x+v[j].y+v[j].z+v[j].w;
    s2 += v[j].x*v[j].x+v[j].y*v[j].y+v[j].z*v[j].z+v[j].w*v[j].w;
  }
  #pragma unroll
  for(int o=32;o>0;o>>=1){ s += __shfl_xor(s,o); s2 += __shfl_xor(s2,o); }
  float mean = s / D;
  float var  = fmaxf(s2 / D - mean*mean, 0.f);
  float inv  = rsqrtf(var + 1e-5f);
  for(int j=0;j<nch;j++){
    int c = j*256 + lane*4;
    ushort4 o4;
    o4.x = f2bu((v[j].x-mean)*inv*g[c]   + bta[c]);
    o4.y = f2bu((v[j].y-mean)*inv*g[c+1] + bta[c+1]);
    o4.z = f2bu((v[j].z-mean)*inv*g[c+2] + bta[c+2]);
    o4.w = f2bu((v[j].w-mean)*inv*g[c+3] + bta[c+3]);
    *(ushort4*)&y[(size_t)row*D + c] = o4;
  }
}

// LN wave-per-row: bf16 in -> bf16 out
__global__ __launch_bounds__(256) void k_ln4b(const bf16* __restrict__ x,
    const float* __restrict__ g, const float* __restrict__ bta,
    bf16* __restrict__ y, int D){
  int row = blockIdx.x*4 + (threadIdx.x>>6);
  int lane = threadIdx.x & 63;
  const unsigned short* xr = (const unsigned short*)(x + (size_t)row*D);
  int nch = D >> 8;
  float4 v[2];
  float s=0.f, s2=0.f;
  for(int j=0;j<nch;j++){
    ushort4 u = *(const ushort4*)&xr[j*256 + lane*4];
    v[j].x = bu2f(u.x); v[j].y = bu2f(u.y); v[j].z = bu2f(u.z); v[j].w = bu2f(u.w);
    s  += v[j].x+v[j].y+v[j].z+v[j].w;
    s2 += v[j].x*v[j].x+v[j].y*v[j].y+v[j].z*v[j].z+v[j].w*v[j].w;
  }
  #pragma unroll
  for(int o=32;o>0;o>>=1){ s += __shfl_xor(s,o); s2 += __shfl_xor(s2,o); }
  float mean = s / D;
  float var  = fmaxf(s2 / D - mean*mean, 0.f);
  float inv  = rsqrtf(var + 1e-5f);
  for(int j=0;j<nch;j++){
    int c = j*256 + lane*4;
    ushort4 o4;
    o4.x = f2bu((v[j].x-mean)*inv*g[c]   + bta[c]);
    o4.y = f2bu((v[j].y-mean)*inv*g[c+1] + bta[c+1]);
    o4.z = f2bu((v[j].z-mean)*inv*g[c+2] + bta[c+2]);
    o4.w = f2bu((v[j].w-mean)*inv*g[c+3] + bta[c+3]);
    *(ushort4*)&y[(size_t)row*D + c] = o4;
  }
}

// rbf attention bias for one encoder block
__global__ void k_db(const float* __restrict__ coord, const float* __restrict__ real,
                     const float* __restrict__ rbfw, float* __restrict__ db){
  int idx = blockIdx.x*256 + threadIdx.x;
  if(idx >= NBATCH*SENC*SENC) return;
  int b = idx/(SENC*SENC), r = idx%(SENC*SENC), q = r/SENC, k = r%SENC;
  float out[NHEAD];
  bool masked = (real[b*NATOM+k]==0.f) || (k==q);
  if(masked){
    #pragma unroll
    for(int h=0;h<NHEAD;h++) out[h] = -1e9f;
  } else {
    float dx = coord[(b*NATOM+q)*3+0] - coord[(b*NATOM+k)*3+0];
    float dy = coord[(b*NATOM+q)*3+1] - coord[(b*NATOM+k)*3+1];
    float dz = coord[(b*NATOM+q)*3+2] - coord[(b*NATOM+k)*3+2];
    float d  = sqrtf(dx*dx+dy*dy+dz*dz + 1e-12f);
    #pragma unroll
    for(int h=0;h<NHEAD;h++) out[h]=0.f;
    for(int rr=0;rr<16;rr++){
      float cen = (10.f/15.f)*rr;
      float e = __expf(-2.f*(d-cen)*(d-cen));
      #pragma unroll
      for(int h=0;h<NHEAD;h++) out[h] += e * rbfw[rr*NHEAD+h];
    }
  }
  #pragma unroll
  for(int h=0;h<NHEAD;h++)
    db[(((size_t)b*NHEAD+h)*SENC + q)*SENC + k] = out[h];
}

// ===== shared MFMA macro =====
#define MFMA_(acc, a, bfr) acc = __builtin_amdgcn_mfma_f32_16x16x32_bf16(a, bfr, acc, 0, 0, 0);

// ===== encoder attention v3: MFMA flash, block=(b,h), 4 waves =====
#define EQKT(kt, acc) { \
  bf16x8 bklo = *(const bf16x8*)&Ks[(kt)*16 + l15][g*8]; \
  bf16x8 bkhi = *(const bf16x8*)&Ks[(kt)*16 + l15][32 + g*8]; \
  MFMA_(acc, aqlo, bklo) MFMA_(acc, aqhi, bkhi) }
#define EBIAS(kt, sv) { \
  const float* dbr = dbb + (qt*16 + g*4)*80 + l15 + 16*(kt); \
  sv[0] = sv[0]*0.125f + dbr[0]; \
  sv[1] = sv[1]*0.125f + dbr[80]; \
  sv[2] = sv[2]*0.125f + dbr[160]; \
  sv[3] = sv[3]*0.125f + dbr[240]; }
#define EMAXJ(j) fmaxf(fmaxf(fmaxf(s0[j],s1[j]),fmaxf(s2[j],s3[j])),s4[j])
#define EEXP(sv) { sv[0]=__expf(sv[0]-m0); sv[1]=__expf(sv[1]-m1); sv[2]=__expf(sv[2]-m2); sv[3]=__expf(sv[3]-m3); }
#define ESUMJ(j) (s0[j]+s1[j]+s2[j]+s3[j]+s4[j])
#define ESTP(kt, sv) { \
  Pw[w][g*4+0][l15+16*(kt)] = f2bu(sv[0]); \
  Pw[w][g*4+1][l15+16*(kt)] = f2bu(sv[1]); \
  Pw[w][g*4+2][l15+16*(kt)] = f2bu(sv[2]); \
  Pw[w][g*4+3][l15+16*(kt)] = f2bu(sv[3]); }
#define EST(ov, ct) { \
  ob[0*HGDIM + (ct)*16 + l15] = __float2bfloat16(ov[0]*i0); \
  ob[1*HGDIM + (ct)*16 + l15] = __float2bfloat16(ov[1]*i1); \
  ob[2*HGDIM + (ct)*16 + l15] = __float2bfloat16(ov[2]*i2); \
  ob[3*HGDIM + (ct)*16 + l15] = __float2bfloat16(ov[3]*i3); }

__global__ __launch_bounds__(256) void k_attn_enc3(
    const bf16* __restrict__ qkvb, const float* __restrict__ db,
    bf16* __restrict__ o_out)
{
  __shared__ unsigned short Qs[80][72];
  __shared__ unsigned short Ks[80][72];
  __shared__ unsigned short Vt[64][104];
  __shared__ unsigned short Pw[4][16][104];
  int bh = blockIdx.x; int h = bh & 7, b = bh >> 3;
  const bf16* base = qkvb + (size_t)b*SENC*1536;
  const float* dbb = db + (size_t)bh*6400;
  int tid = threadIdx.x;
  int w = tid >> 6, lane = tid & 63;
  int l15 = lane & 15, g = lane >> 4;
  for(int c = tid; c < 640; c += 256){
    int r = c >> 3, p = c & 7;
    *(uint4*)&Qs[r][p*8] = *(const uint4*)(base + (size_t)r*1536 + h*64 + p*8);
    *(uint4*)&Ks[r][p*8] = *(const uint4*)(base + (size_t)r*1536 + 512 + h*64 + p*8);
  }
  for(int c = tid; c < 80*64; c += 256){
    int k = c >> 6, d = c & 63;
    Vt[d][k] = *(const unsigned short*)(base + (size_t)k*1536 + 1024 + h*64 + d);
  }
  for(int c = tid; c < 64*16; c += 256){
    int d = c >> 4, cc = c & 15;
    Vt[d][80+cc] = 0;
  }
  {
    int r = lane >> 2, c4 = (lane & 3)*4;
    ushort4 zz = {0,0,0,0};
    *(ushort4*)&Pw[w][r][80 + c4] = zz;
  }
  __syncthreads();
  for(int qt = w; qt < 5; qt += 4){
    bf16x8 aqlo = *(const bf16x8*)&Qs[qt*16 + l15][g*8];
    bf16x8 aqhi = *(const bf16x8*)&Qs[qt*16 + l15][32 + g*8];
    f32x4 z = {0.f,0.f,0.f,0.f};
    f32x4 s0=z,s1=z,s2=z,s3=z,s4=z;
    EQKT(0,s0) EQKT(1,s1) EQKT(2,s2) EQKT(3,s3) EQKT(4,s4)
    EBIAS(0,s0) EBIAS(1,s1) EBIAS(2,s2) EBIAS(3,s3) EBIAS(4,s4)
    float m0=EMAXJ(0), m1=EMAXJ(1), m2=EMAXJ(2), m3=EMAXJ(3);
    #pragma unroll
    for(int off=1; off<16; off<<=1){
      m0 = fmaxf(m0, __shfl_xor(m0, off));
      m1 = fmaxf(m1, __shfl_xor(m1, off));
      m2 = fmaxf(m2, __shfl_xor(m2, off));
      m3 = fmaxf(m3, __shfl_xor(m3, off));
    }
    EEXP(s0) EEXP(s1) EEXP(s2) EEXP(s3) EEXP(s4)
    float l0=ESUMJ(0), l1=ESUMJ(1), l2=ESUMJ(2), l3=ESUMJ(3);
    #pragma unroll
    for(int off=1; off<16; off<<=1){
      l0 += __shfl_xor(l0, off);
      l1 += __shfl_xor(l1, off);
      l2 += __shfl_xor(l2, off);
      l3 += __shfl_xor(l3, off);
    }
    ESTP(0,s0) ESTP(1,s1) ESTP(2,s2) ESTP(3,s3) ESTP(4,s4)
    f32x4 o0=z, o1=z, o2=z, o3=z;
    #pragma unroll
    for(int kc=0; kc<3; kc++){
      bf16x8 ap = *(const bf16x8*)&Pw[w][l15][kc*32 + g*8];
      bf16x8 v0 = *(const bf16x8*)&Vt[l15][kc*32 + g*8];
      bf16x8 v1 = *(const bf16x8*)&Vt[16 + l15][kc*32 + g*8];
      bf16x8 v2 = *(const bf16x8*)&Vt[32 + l15][kc*32 + g*8];
      bf16x8 v3 = *(const bf16x8*)&Vt[48 + l15][kc*32 + g*8];
      MFMA_(o0, ap, v0) MFMA_(o1, ap, v1) MFMA_(o2, ap, v2) MFMA_(o3, ap, v3)
    }
    float i0 = 1.f/l0, i1 = 1.f/l1, i2 = 1.f/l2, i3 = 1.f/l3;
    bf16* ob = o_out + ((size_t)(b*SENC + qt*16 + g*4))*HGDIM + h*64;
    EST(o0, 0) EST(o1, 1) EST(o2, 2) EST(o3, 3)
  }
}

// ===== decoder attention v5: MFMA flash attention, block=(b,h), 4 waves =====
#define QKT(kt, acc) { bf16x8 bk = *(const bf16x8*)&Ks[(kt)*16 + l15][g*8]; MFMA_(acc, aq, bk) }
#define SMSC(sv, mbv) { sv[0]=sv[0]*SCAL+(mbv); sv[1]=sv[1]*SCAL+(mbv); sv[2]=sv[2]*SCAL+(mbv); sv[3]=sv[3]*SCAL+(mbv); }
#define MAXJ(j) fmaxf(fmaxf(fmaxf(fmaxf(s0[j],s1[j]),fmaxf(s2[j],s3[j])),fmaxf(fmaxf(s4[j],s5[j]),fmaxf(s6[j],s7[j]))),fmaxf(s8[j],s9[j]))
#define EXPS(sv) { sv[0]=__expf(sv[0]-m0); sv[1]=__expf(sv[1]-m1); sv[2]=__expf(sv[2]-m2); sv[3]=__expf(sv[3]-m3); }
#define SUMJ(j) (s0[j]+s1[j]+s2[j]+s3[j]+s4[j]+s5[j]+s6[j]+s7[j]+s8[j]+s9[j])
#define STP(kt, sv) { \
  Pw[w][g*4+0][l15+16*(kt)] = f2bu(sv[0]); \
  Pw[w][g*4+1][l15+16*(kt)] = f2bu(sv[1]); \
  Pw[w][g*4+2][l15+16*(kt)] = f2bu(sv[2]); \
  Pw[w][g*4+3][l15+16*(kt)] = f2bu(sv[3]); }

__global__ __launch_bounds__(256) void k_attn_dec5(
    const bf16* __restrict__ qkvb, const float* __restrict__ real,
    bf16* __restrict__ o_out)
{
  __shared__ unsigned short Qs[160][40];
  __shared__ unsigned short Ks[160][40];
  __shared__ unsigned short Vt[32][168];
  __shared__ unsigned short Pw[4][16][168];
  __shared__ float mb[160];
  const float SCAL = 0.17677669529663689f;
  int bh = blockIdx.x; int h = bh & 7, b = bh >> 3;
  const bf16* base = qkvb + (size_t)b*SDEC*768;
  int tid = threadIdx.x;
  int w = tid >> 6, lane = tid & 63;
  int l15 = lane & 15, g = lane >> 4;
  for(int c = tid; c < 160*4; c += 256){
    int r = c >> 2, p = c & 3;
    *(uint4*)&Qs[r][p*8] = *(const uint4*)(base + (size_t)r*768 + h*32 + p*8);
    *(uint4*)&Ks[r][p*8] = *(const uint4*)(base + (size_t)r*768 + 256 + h*32 + p*8);
  }
  for(int c = tid; c < 160*32; c += 256){
    int k = c >> 5, d = c & 31;
    Vt[d][k] = *(const unsigned short*)(base + (size_t)k*768 + 512 + h*32 + d);
  }
  for(int k = tid; k < 160; k += 256){
    int kk = (k<80)?k:k-80;
    mb[k] = (real[b*NATOM+kk]==0.f) ? -1e9f : 0.f;
  }
  __syncthreads();
  float mb0=mb[l15],     mb1=mb[l15+16],  mb2=mb[l15+32],  mb3=mb[l15+48],  mb4=mb[l15+64];
  float mb5=mb[l15+80],  mb6=mb[l15+96],  mb7=mb[l15+112], mb8=mb[l15+128], mb9=mb[l15+144];
  for(int qt = w; qt < 10; qt += 4){
    bf16x8 aq = *(const bf16x8*)&Qs[qt*16 + l15][g*8];
    f32x4 z = {0.f,0.f,0.f,0.f};
    f32x4 s0=z,s1=z,s2=z,s3=z,s4=z,s5=z,s6=z,s7=z,s8=z,s9=z;
    QKT(0,s0) QKT(1,s1) QKT(2,s2) QKT(3,s3) QKT(4,s4)
    QKT(5,s5) QKT(6,s6) QKT(7,s7) QKT(8,s8) QKT(9,s9)
    SMSC(s0,mb0) SMSC(s1,mb1) SMSC(s2,mb2) SMSC(s3,mb3) SMSC(s4,mb4)
    SMSC(s5,mb5) SMSC(s6,mb6) SMSC(s7,mb7) SMSC(s8,mb8) SMSC(s9,mb9)
    float m0=MAXJ(0), m1=MAXJ(1), m2=MAXJ(2), m3=MAXJ(3);
    #pragma unroll
    for(int off=1; off<16; off<<=1){
      m0 = fmaxf(m0, __shfl_xor(m0, off));
      m1 = fmaxf(m1, __shfl_xor(m1, off));
      m2 = fmaxf(m2, __shfl_xor(m2, off));
      m3 = fmaxf(m3, __shfl_xor(m3, off));
    }
    EXPS(s0) EXPS(s1) EXPS(s2) EXPS(s3) EXPS(s4)
    EXPS(s5) EXPS(s6) EXPS(s7) EXPS(s8) EXPS(s9)
    float l0=SUMJ(0), l1=SUMJ(1), l2=SUMJ(2), l3=SUMJ(3);
    #pragma unroll
    for(int off=1; off<16; off<<=1){
      l0 += __shfl_xor(l0, off);
      l1 += __shfl_xor(l1, off);
      l2 += __shfl_xor(l2, off);
      l3 += __shfl_xor(l3, off);
    }
    STP(0,s0) STP(1,s1) STP(2,s2) STP(3,s3) STP(4,s4)
    STP(5,s5) STP(6,s6) STP(7,s7) STP(8,s8) STP(9,s9)
    f32x4 o0 = z, o1 = z;
    #pragma unroll
    for(int kt=0; kt<5; kt++){
      bf16x8 ap = *(const bf16x8*)&Pw[w][l15][kt*32 + g*8];
      bf16x8 v0 = *(const bf16x8*)&Vt[l15][kt*32 + g*8];
      bf16x8 v1 = *(const bf16x8*)&Vt[16 + l15][kt*32 + g*8];
      MFMA_(o0, ap, v0)
      MFMA_(o1, ap, v1)
    }
    float i0 = 1.f/l0, i1 = 1.f/l1, i2 = 1.f/l2, i3 = 1.f/l3;
    bf16* ob = o_out + ((size_t)(b*SDEC + qt*16 + g*4))*HIDDIM + h*32;
    ob[0*HIDDIM + l15]      = __float2bfloat16(o0[0]*i0);
    ob[1*HIDDIM + l15]      = __float2bfloat16(o0[1]*i1);
    ob[2*HIDDIM + l15]      = __float2bfloat16(o0[2]*i2);
    ob[3*HIDDIM + l15]      = __float2bfloat16(o0[3]*i3);
    ob[0*HIDDIM + 16 + l15] = __float2bfloat16(o1[0]*i0);
    ob[1*HIDDIM + 16 + l15] = __float2bfloat16(o1[1]*i1);
    ob[2*HIDDIM + 16 + l15] = __float2bfloat16(o1[2]*i2);
    ob[3*HIDDIM + 16 + l15] = __float2bfloat16(o1[3]*i3);
  }
}

// ===== shared MFM macro =====
#define MFM(accv, av, bv) accv = __builtin_amdgcn_mfma_f32_16x16x32_bf16(av, bv, accv, 0, 0, 0);

// ===== MFMA bf16 GEMM v10: 64x128, BK=64, depth-2 register prefetch =====
#define EPIM8(accv, rr, cc) { \
  int col = col0 + w*32 + (cc)*16 + l15; \
  float bi = bias ? bias[col] : 0.f; \
  _Pragma("unroll") \
  for(int j=0;j<4;j++){ \
    int row = row0 + (rr)*16 + g*4 + j; \
    float v = accv[j] + bi; \
    if(resid) v += resid[(size_t)row*Nw + col]; \
    if(act==1) v = v/(1.f+__expf(-v)); \
    if(Cf) Cf[(size_t)row*Nw + col] = v; \
    else   Cb[(size_t)row*Nw + col] = __float2bfloat16(v); } }

#define SUBSTEP8(s) { \
  int ch = ((s)*4 + g) ^ sw7; \
  bf16x8 a0 = *(const bf16x8*)&As4[l15][ch]; \
  bf16x8 a1 = *(const bf16x8*)&As4[16 + l15][ch]; \
  bf16x8 a2 = *(const bf16x8*)&As4[32 + l15][ch]; \
  bf16x8 a3 = *(const bf16x8*)&As4[48 + l15][ch]; \
  bf16x8 b0 = *(const bf16x8*)&Bs4[w*32 + l15][ch]; \
  bf16x8 b1 = *(const bf16x8*)&Bs4[w*32 + 16 + l15][ch]; \
  MFM(c00, a0, b0) MFM(c01, a0, b1) \
  MFM(c10, a1, b0) MFM(c11, a1, b1) \
  MFM(c20, a2, b0) MFM(c21, a2, b1) \
  MFM(c30, a3, b0) MFM(c31, a3, b1) }

#define LOADSET(aw0, aw1, bw0, bw1, bw2, bw3, koff) { \
  const uint4* asrc = (const uint4*)(aP + (koff)); \
  const uint4* bsrc = (const uint4*)(bP + (koff)); \
  aw0=asrc[0]; aw1=asrc[1]; \
  bw0=bsrc[0]; bw1=bsrc[1]; bw2=bsrc[2]; bw3=bsrc[3]; }

#define STORESET(aw0, aw1, bw0, bw1, bw2, bw3) { \
  As4[arow4][(2*aq+0)^swA] = aw0; \
  As4[arow4][(2*aq+1)^swA] = aw1; \
  Bs4[brow][(bbp+0)^swB] = bw0; \
  Bs4[brow][(bbp+1)^swB] = bw1; \
  Bs4[brow][(bbp+2)^swB] = bw2; \
  Bs4[brow][(bbp+3)^swB] = bw3; }

__global__ __launch_bounds__(256) void k_gemm_mfma10(
    const bf16* __restrict__ A, const bf16* __restrict__ WT,
    const float* __restrict__ bias, const float* __restrict__ resid,
    float* __restrict__ Cf, bf16* __restrict__ Cb,
    int M, int K, int Nw, int act)
{
  __shared__ uint4 As4[64][8];
  __shared__ uint4 Bs4[128][8];
  int tid = threadIdx.x;
  int w = tid >> 6, lane = tid & 63;
  int l15 = lane & 15, g = lane >> 4;
  int lin = blockIdx.x + gridDim.x*blockIdx.y;
  int bcol = lin / gridDim.y;
  int brw  = lin - bcol*gridDim.y;
  int row0 = brw*64, col0 = bcol*128;
  int arow4 = tid >> 2, aq = tid & 3;
  int swA = arow4 & 7;
  int brow = tid >> 1, bhalf = tid & 1;
  int swB = brow & 7;
  int sw7 = l15 & 7;
  int bbp = bhalf*4;
  const bf16* aP = A  + (size_t)(row0+arow4)*K + aq*16;
  const bf16* bP = WT + (size_t)(col0+brow)*K + bhalf*32;
  f32x4 z = {0.f,0.f,0.f,0.f};
  f32x4 c00=z,c01=z,c10=z,c11=z,c20=z,c21=z,c30=z,c31=z;
  uint4 aA0,aA1,bA0,bA1,bA2,bA3;
  uint4 aB0,aB1,bB0,bB1,bB2,bB3;
  LOADSET(aA0,aA1,bA0,bA1,bA2,bA3, 0)
  LOADSET(aB0,aB1,bB0,bB1,bB2,bB3, 64)
  for(int k0=0;k0<K;k0+=128){
    STORESET(aA0,aA1,bA0,bA1,bA2,bA3)
    __syncthreads();
    if(k0+128 < K){ LOADSET(aA0,aA1,bA0,bA1,bA2,bA3, k0+128) }
    SUBSTEP8(0)
    SUBSTEP8(1)
    __syncthreads();
    STORESET(aB0,aB1,bB0,bB1,bB2,bB3)
    __syncthreads();
    if(k0+192 < K){ LOADSET(aB0,aB1,bB0,bB1,bB2,bB3, k0+192) }
    SUBSTEP8(0)
    SUBSTEP8(1)
    __syncthreads();
  }
  EPIM8(c00, 0, 0) EPIM8(c01, 0, 1)
  EPIM8(c10, 1, 0) EPIM8(c11, 1, 1)
  EPIM8(c20, 2, 0) EPIM8(c21, 2, 1)
  EPIM8(c30, 3, 0) EPIM8(c31, 3, 1)
}

// ===== MFMA bf16 GEMM v11: 64x64 tile, BK=64, high occupancy for small-N GEMMs =====
#define EPIM11(accv, rr) { \
  int col = col0 + w*16 + l15; \
  float bi = bias ? bias[col] : 0.f; \
  _Pragma("unroll") \
  for(int j=0;j<4;j++){ \
    int row = row0 + (rr)*16 + g*4 + j; \
    float v = accv[j] + bi; \
    if(resid) v += resid[(size_t)row*Nw + col]; \
    if(act==1) v = v/(1.f+__expf(-v)); \
    if(Cf) Cf[(size_t)row*Nw + col] = v; \
    else   Cb[(size_t)row*Nw + col] = __float2bfloat16(v); } }

#define SUBSTEP11(s) { \
  int ch = ((s)*4 + g) ^ sw7; \
  bf16x8 a0 = *(const bf16x8*)&As4[l15][ch]; \
  bf16x8 a1 = *(const bf16x8*)&As4[16 + l15][ch]; \
  bf16x8 a2 = *(const bf16x8*)&As4[32 + l15][ch]; \
  bf16x8 a3 = *(const bf16x8*)&As4[48 + l15][ch]; \
  bf16x8 b0 = *(const bf16x8*)&Bs4[w*16 + l15][ch]; \
  MFM(c0, a0, b0) MFM(c1, a1, b0) MFM(c2, a2, b0) MFM(c3, a3, b0) }

__global__ __launch_bounds__(256) void k_gemm_mfma11(
    const bf16* __restrict__ A, const bf16* __restrict__ WT,
    const float* __restrict__ bias, const float* __restrict__ resid,
    float* __restrict__ Cf, bf16* __restrict__ Cb,
    int M, int K, int Nw, int act)
{
  __shared__ uint4 As4[64][8];
  __shared__ uint4 Bs4[64][8];
  int tid = threadIdx.x;
  int w = tid >> 6, lane = tid & 63;
  int l15 = lane & 15, g = lane >> 4;
  int lin = blockIdx.x + gridDim.x*blockIdx.y;
  int bcol = lin / gridDim.y;
  int brw  = lin - bcol*gridDim.y;
  int row0 = brw*64, col0 = bcol*64;
  int arow = tid >> 2, apair = (tid & 3)*2;
  int swr = arow & 7;
  int sw7 = l15 & 7;
  const bf16* aP = A  + (size_t)(row0+arow)*K + apair*8;
  const bf16* bP = WT + (size_t)(col0+arow)*K + apair*8;
  f32x4 z = {0.f,0.f,0.f,0.f};
  f32x4 c0=z,c1=z,c2=z,c3=z;
  uint4 av0,av1,bv0,bv1;
  {
    const uint4* asrc = (const uint4*)aP;
    const uint4* bsrc = (const uint4*)bP;
    av0=asrc[0]; av1=asrc[1];
    bv0=bsrc[0]; bv1=bsrc[1];
  }
  for(int k0=0;k0<K;k0+=64){
    As4[arow][(apair+0)^swr] = av0;
    As4[arow][(apair+1)^swr] = av1;
    Bs4[arow][(apair+0)^swr] = bv0;
    Bs4[arow][(apair+1)^swr] = bv1;
    __syncthreads();
    int kn = k0 + 64;
    if(kn < K){
      const uint4* asrc = (const uint4*)(aP + kn);
      const uint4* bsrc = (const uint4*)(bP + kn);
      av0=asrc[0]; av1=asrc[1];
      bv0=bsrc[0]; bv1=bsrc[1];
    }
    SUBSTEP11(0)
    SUBSTEP11(1)
    __syncthreads();
  }
  EPIM11(c0, 0) EPIM11(c1, 1) EPIM11(c2, 2) EPIM11(c3, 3)
}

// ===== tiny-N GEMM: 16 rows/block, A tile + W staged in LDS, K=256, Nw<=16 =====
__global__ __launch_bounds__(256) void k_gemm_tiny(
    const bf16* __restrict__ A, const float* __restrict__ W,
    const float* __restrict__ bias, float* __restrict__ C,
    int Nw, int act)
{
  __shared__ unsigned short As[16][264];
  __shared__ float Ws[4096];
  int tid = threadIdx.x;
  int row0 = blockIdx.x*16;
  int ar = tid >> 4, ac = (tid & 15) * 16;
  const uint4* asrc = (const uint4*)(A + (size_t)(row0+ar)*256 + ac);
  *(uint4*)&As[ar][ac]   = asrc[0];
  *(uint4*)&As[ar][ac+8] = asrc[1];
  int wtot = 256*Nw;
  for(int i=tid; i<wtot; i+=256) Ws[i] = W[i];
  __syncthreads();
  int row = tid >> 4, col = tid & 15;
  if(col < Nw){
    float acc = bias ? bias[col] : 0.f;
    #pragma unroll 8
    for(int k=0;k<256;k++)
      acc += bu2f(As[row][k]) * Ws[k*Nw+col];
    if(act==1) acc = acc/(1.f+__expf(-acc));
    C[(size_t)(row0+row)*Nw + col] = acc;
  }
}

__global__ __launch_bounds__(256) void k_kl(const float* __restrict__ mom,
    const float* __restrict__ real, float* __restrict__ part){
  int i = blockIdx.x*256 + threadIdx.x;
  float s = 0.f;
  if(i < ROWS_E){
    const float* m = mom + (size_t)i*12;
    float acc = 0.f;
    #pragma unroll
    for(int d=0;d<6;d++){ float mu=m[d], lv=m[6+d]; acc += 1.f + lv - mu*mu - expf(lv); }
    s = acc * real[i];
  }
  #pragma unroll
  for(int o=32;o>0;o>>=1) s += __shfl_xor(s,o);
  __shared__ float r[4];
  if((threadIdx.x&63)==0) r[threadIdx.x>>6]=s;
  __syncthreads();
  if(threadIdx.x==0) part[blockIdx.x] = r[0]+r[1]+r[2]+r[3];
}

__global__ void k_klfin(const float* __restrict__ part, float* __restrict__ o){
  float s=0.f;
  for(int i=0;i<40;i++) s += part[i];
  *o = -0.5f * (s/(float)ROWS_E) * 1e-6f;
}

// h*real -> bf16
__global__ void k_cvtrs(const float* __restrict__ h, const float* __restrict__ real,
                        bf16* __restrict__ o){
  int idx = blockIdx.x*256 + threadIdx.x;
  if(idx >= ROWS_E*HGDIM) return;
  int row = idx >> 9;
  o[idx] = __float2bfloat16(h[idx]*real[row]);
}

__global__ __launch_bounds__(256) void k_build_x(
  const float* __restrict__ coord_t, const float* __restrict__ atomics_t, const float* __restrict__ tin,
  const float* __restrict__ qout_w, const float* __restrict__ qout_b, const float* __restrict__ cond,
  const float* __restrict__ lin_w, const float* __restrict__ atom_emb,
  const float* __restrict__ mom, const float* __restrict__ real, float* __restrict__ x)
{
  int idx = blockIdx.x*256 + threadIdx.x;
  if(idx >= NBATCH*SDEC*HIDDIM) return;
  int c = idx & 255; int rowg = idx >> 8; int s = rowg % SDEC; int b = rowg / SDEC;
  int n = (s<NATOM)? s : s-NATOM;
  int j = c >> 1;
  float div = __expf(-(float)(2*j) * (9.210340371976184f/256.f));
  float ang = (float)n * div;
  float pe = (c & 1) ? __cosf(ang) : __sinf(ang);
  float rl = real[b*NATOM + n];
  float v;
  if(s < NATOM){
    int rown = b*NATOM + n;
    float cl = 0.f;
    #pragma unroll
    for(int a=0;a<3;a++) cl += coord_t[rown*3+a] * lin_w[a*HIDDIM+c];
    int bi=0; float bv = atomics_t[rown*16];
    for(int a=1;a<16;a++){ float vv=atomics_t[rown*16+a]; if(vv>bv){bv=vv; bi=a;} }
    float ae = atom_emb[bi*HIDDIM+c];
    float tb = tin[b];
    float tf;
    if(c < 128){
      float fr = __expf(-(float)c * (5.298317366548036f/128.f));
      tf = __sinf(tb*200.f*fr);
    } else {
      float fr = __expf(-(float)(c-128) * (5.298317366548036f/128.f));
      tf = __cosf(tb*200.f*fr);
    }
    v = (cl + ae + pe + tf)*rl + cond[c];
  } else {
    int rown = b*NATOM + n;
    const float* mp = mom + (size_t)rown*12;
    float s2 = qout_b[c];
    #pragma unroll
    for(int d=0;d<6;d++) s2 += mp[d]*qout_w[d*HIDDIM+c];
    v = (s2 + pe)*rl + cond[HIDDIM+c];
  }
  x[idx] = v;
}

// h_out -> bf16 only
__global__ void k_hout(const float* __restrict__ x, const float* __restrict__ real,
                       bf16* __restrict__ h_out_b){
  int idx = blockIdx.x*256 + threadIdx.x;
  if(idx >= ROWS_E*HIDDIM) return;
  int c = idx & 255, row = idx >> 8;
  int n = row % NATOM, b = row / NATOM;
  float v = x[((size_t)(b*SDEC+n))*HIDDIM + c] * real[row];
  h_out_b[idx] = __float2bfloat16(v);
}

// ---------------- launch ----------------
extern "C" void kernel_launch(void* const* d_in, const int* in_sizes, int n_in,
                              void* d_out, int out_size, void* d_ws, size_t ws_size,
                              hipStream_t stream){
  (void)in_sizes; (void)n_in; (void)out_size;
  const float* coord_ori   = (const float*)d_in[0];
  const float* atomics_ori = (const float*)d_in[1];
  const unsigned char* pmask = (const unsigned char*)d_in[2];
  const float* coord_t     = (const float*)d_in[3];
  const float* atomics_t   = (const float*)d_in[4];
  const float* t_in        = (const float*)d_in[5];
  const float* enc_embed_w = (const float*)d_in[6];
  const float* rbf_w       = (const float*)d_in[7];
  const float* e_qkv_w=(const float*)d_in[8];  const float* e_qkv_b=(const float*)d_in[9];
  const float* e_out_w=(const float*)d_in[10]; const float* e_out_b=(const float*)d_in[11];
  const float* e_ff1_w=(const float*)d_in[12]; const float* e_ff1_b=(const float*)d_in[13];
  const float* e_ff2_w=(const float*)d_in[14]; const float* e_ff2_b=(const float*)d_in[15];
  const float* e_ln1_g=(const float*)d_in[16]; const float* e_ln1_b=(const float*)d_in[17];
  const float* e_ln2_g=(const float*)d_in[18]; const float* e_ln2_b=(const float*)d_in[19];
  const float* enc_proj_w=(const float*)d_in[20];
  const float* quant_w=(const float*)d_in[21]; const float* quant_b=(const float*)d_in[22];
  const float* qout_w=(const float*)d_in[23];  const float* qout_b=(const float*)d_in[24];
  const float* cond_embed=(const float*)d_in[25];
  const float* lin_embed_w=(const float*)d_in[26];
  const float* atom_embed=(const float*)d_in[27];
  const float* d_qkv_w=(const float*)d_in[28]; const float* d_qkv_b=(const float*)d_in[29];
  const float* d_ow   =(const float*)d_in[30]; const float* d_ob   =(const float*)d_in[31];
  const float* d_ff1_w=(const float*)d_in[32]; const float* d_ff1_b=(const float*)d_in[33];
  const float* d_ff2_w=(const float*)d_in[34]; const float* d_ff2_b=(const float*)d_in[35];
  const float* d_ln1_g=(const float*)d_in[36]; const float* d_ln1_b=(const float*)d_in[37];
  const float* d_ln2_g=(const float*)d_in[38]; const float* d_ln2_b=(const float*)d_in[39];
  const float* oc_ln_g=(const float*)d_in[40]; const float* oc_ln_b=(const float*)d_in[41];
  const float* oc_w   =(const float*)d_in[42];
  const float* oa1_w  =(const float*)d_in[43]; const float* oa1_b=(const float*)d_in[44];
  const float* oa2_w  =(const float*)d_in[45]; const float* oa2_b=(const float*)d_in[46];

  float* ws   = (float*)d_ws;
  float* real = ws + OFF_REAL;
  int*   flag = (int*)(ws + OFF_FLAG);
  float* h    = ws + OFF_H;
  bf16*  qkvb = (bf16*)(ws + OFF_QKVB);
  float* db   = ws + OFF_DB;
  bf16*  lnb  = (bf16*)(ws + OFF_LNB);
  bf16*  aob  = (bf16*)(ws + OFF_AOB);
  bf16*  mid  = (bf16*)(ws + OFF_MID);
  float* mom  = ws + OFF_MOM;
  float* klp  = ws + OFF_KL;
  bf16*  wt   = (bf16*)(ws + OFF_WT);
  float* out  = (float*)d_out;

  if(ws_size < NEED_BYTES){
    k_wsfail<<<1,64,0,stream>>>(out, 1.0e6f + (float)(ws_size>>20));
    return;
  }

  // one-time weight transposes (fp32 [K][N] -> bf16 [N][K])
  k_wt<<<dim3(48,16,4),256,0,stream>>>(e_qkv_w,  wt+WT_EQKV, 512, 1536);
  k_wt<<<dim3(16,16,4),256,0,stream>>>(e_out_w,  wt+WT_EOUT, 512, 512);
  k_wt<<<dim3(64,16,4),256,0,stream>>>(e_ff1_w,  wt+WT_EFF1, 512, 2048);
  k_wt<<<dim3(16,64,4),256,0,stream>>>(e_ff2_w,  wt+WT_EFF2, 2048, 512);
  k_wt<<<dim3(8,16,1), 256,0,stream>>>(enc_proj_w, wt+WT_PROJ, 512, 256);
  k_wt<<<dim3(24,8,8), 256,0,stream>>>(d_qkv_w,  wt+WT_DQKV, 256, 768);
  k_wt<<<dim3(8,8,8),  256,0,stream>>>(d_ow,     wt+WT_DOW,  256, 256);
  k_wt<<<dim3(32,8,8), 256,0,stream>>>(d_ff1_w,  wt+WT_DFF1, 256, 1024);
  k_wt<<<dim3(8,32,8), 256,0,stream>>>(d_ff2_w,  wt+WT_DFF2, 1024, 256);
  k_wt<<<dim3(8,8,1),  256,0,stream>>>(oa1_w,    wt+WT_OA1,  256, 256);

  k_maskmode<<<1,256,0,stream>>>(pmask, flag);
  k_real <<<40,   256, 0, stream>>>(pmask, flag, real);
  k_embed<<<20480,256, 0, stream>>>(atomics_ori, enc_embed_w, h);

  // ===== encoder =====
  for(int i=0;i<4;i++){
    k_ln4<<<ROWS_E/4,256,0,stream>>>(h, e_ln1_g+i*HGDIM, e_ln1_b+i*HGDIM, lnb, HGDIM);
    k_gemm_mfma10<<<dim3(12,160),256,0,stream>>>(lnb, wt+WT_EQKV+(size_t)i*512*1536,
        e_qkv_b+i*3*HGDIM, nullptr, nullptr, qkvb, ROWS_E, HGDIM, 3*HGDIM, 0);
    k_db<<<3200,256,0,stream>>>(coord_ori, real, rbf_w + i*16*NHEAD, db);
    k_attn_enc3<<<NBATCH*NHEAD,256,0,stream>>>(qkvb, db, aob);
    k_gemm_mfma11<<<dim3(8,160),256,0,stream>>>(aob, wt+WT_EOUT+(size_t)i*512*512,
        e_out_b+i*HGDIM, h, h, nullptr, ROWS_E, HGDIM, HGDIM, 0);
    k_ln4<<<ROWS_E/4,256,0,stream>>>(h, e_ln2_g+i*HGDIM, e_ln2_b+i*HGDIM, lnb, HGDIM);
    k_gemm_mfma10<<<dim3(16,160),256,0,stream>>>(lnb, wt+WT_EFF1+(size_t)i*512*2048,
        e_ff1_b+i*4*HGDIM, nullptr, nullptr, mid, ROWS_E, HGDIM, 4*HGDIM, 1);
    k_gemm_mfma11<<<dim3(8,160),256,0,stream>>>(mid, wt+WT_EFF2+(size_t)i*2048*512,
        e_ff2_b+i*HGDIM, h, h, nullptr, ROWS_E, 4*HGDIM, HGDIM, 0);
  }

  k_cvtrs<<<20480,256,0,stream>>>(h, real, lnb);
  k_gemm_mfma11<<<dim3(4,160),256,0,stream>>>(lnb, wt+WT_PROJ,
      nullptr, nullptr, nullptr, aob, ROWS_E, HGDIM, HIDDIM, 0);
  k_gemm_tiny<<<640,256,0,stream>>>(aob, quant_w, quant_b, mom, 12, 0);
  k_kl   <<<40,256,0,stream>>>(mom, real, klp);
  k_klfin<<<1,1,0,stream>>>(klp, out + 194560);

  k_build_x<<<20480,256,0,stream>>>(coord_t, atomics_t, t_in, qout_w, qout_b,
      cond_embed, lin_embed_w, atom_embed, mom, real, h);

  // ===== decoder =====
  for(int i=0;i<8;i++){
    k_ln4<<<ROWS_D/4,256,0,stream>>>(h, d_ln1_g+i*HIDDIM, d_ln1_b+i*HIDDIM, lnb, HIDDIM);
    k_gemm_mfma10<<<dim3(6,320),256,0,stream>>>(lnb, wt+WT_DQKV+(size_t)i*256*768,
        d_qkv_b+i*3*HIDDIM, nullptr, nullptr, qkvb, ROWS_D, HIDDIM, 3*HIDDIM, 0);
    k_attn_dec5<<<NBATCH*NHEAD,256,0,stream>>>(qkvb, real, aob);
    k_gemm_mfma11<<<dim3(4,320),256,0,stream>>>(aob, wt+WT_DOW+(size_t)i*256*256,
        d_ob+i*HIDDIM, h, h, nullptr, ROWS_D, HIDDIM, HIDDIM, 0);
    k_ln4<<<ROWS_D/4,256,0,stream>>>(h, d_ln2_g+i*HIDDIM, d_ln2_b+i*HIDDIM, lnb, HIDDIM);
    k_gemm_mfma10<<<dim3(8,320),256,0,stream>>>(lnb, wt+WT_DFF1+(size_t)i*256*1024,
        d_ff1_b+i*4*HIDDIM, nullptr, nullptr, mid, ROWS_D, HIDDIM, 4*HIDDIM, 1);
    k_gemm_mfma11<<<dim3(4,320),256,0,stream>>>(mid, wt+WT_DFF2+(size_t)i*1024*256,
        d_ff2_b+i*HIDDIM, h, h, nullptr, ROWS_D, 4*HIDDIM, HIDDIM, 0);
  }

  // ===== heads =====
  k_hout<<<10240,256,0,stream>>>(h, real, aob);
  k_ln4b<<<ROWS_E/4,256,0,stream>>>(aob, oc_ln_g, oc_ln_b, lnb, HIDDIM);
  k_gemm_tiny<<<640,256,0,stream>>>(lnb, oc_w, nullptr, out, 3, 0);
  k_gemm_mfma11<<<dim3(4,160),256,0,stream>>>(aob, wt+WT_OA1, oa1_b, nullptr,
      nullptr, mid, ROWS_E, HIDDIM, HIDDIM, 1);
  k_gemm_tiny<<<640,256,0,stream>>>(mid, oa2_w, oa2_b, out + 30720, 16, 0);
}